// Round 11
// baseline (494.193 us; speedup 1.0000x reference)
//
#include <hip/hip_runtime.h>
#include <math.h>

#define NEG_INF -3.402823466e38f

typedef __attribute__((ext_vector_type(8))) short bf16x8;
typedef __attribute__((ext_vector_type(4))) float f32x4;

__device__ __forceinline__ void gload_lds16(const unsigned short* g, unsigned short* l) {
  __builtin_amdgcn_global_load_lds(
      (const __attribute__((address_space(1))) unsigned int*)g,
      (__attribute__((address_space(3))) unsigned int*)l, 16, 0, 0);
}
__device__ __forceinline__ void gload_lds16f(const float* g, float* l) {
  __builtin_amdgcn_global_load_lds(
      (const __attribute__((address_space(1))) unsigned int*)g,
      (__attribute__((address_space(3))) unsigned int*)l, 16, 0, 0);
}

__device__ __forceinline__ unsigned short f2bf(float f) {
  union { float f; unsigned int u; } a; a.f = f;
  unsigned int u = a.u;
  return (unsigned short)((u + 0x7fffu + ((u >> 16) & 1u)) >> 16);
}
__device__ __forceinline__ float bf2f(unsigned short h) {
  union { unsigned int u; float f; } a; a.u = ((unsigned int)h) << 16; return a.f;
}

// exact 3-term truncation split (h+m+l == v bit-exactly for normal fp32)
__device__ __forceinline__ void split3_1(float v, unsigned short& h,
                                         unsigned short& m, unsigned short& l) {
  union { float f; unsigned int u; } x, hh, rr, mm, ss;
  x.f = v;
  h = (unsigned short)(x.u >> 16); hh.u = x.u & 0xffff0000u;
  rr.f = x.f - hh.f;
  m = (unsigned short)(rr.u >> 16); mm.u = rr.u & 0xffff0000u;
  ss.f = rr.f - mm.f;
  l = (unsigned short)(ss.u >> 16);
}

// pairwise 3-term truncation split: 8 f32 -> hi/mid/lo bf16x8 (same bit ops).
__device__ __forceinline__ void split3_8(f32x4 a, f32x4 b,
                                         bf16x8& hi, bf16x8& md, bf16x8& lo) {
  union { bf16x8 v; unsigned int u[4]; } H, M, L;
  float f[8];
  f[0]=a[0]; f[1]=a[1]; f[2]=a[2]; f[3]=a[3];
  f[4]=b[0]; f[5]=b[1]; f[6]=b[2]; f[7]=b[3];
#pragma unroll
  for (int p = 0; p < 4; ++p) {
    union { float f; unsigned int u; } x0, x1, h0, h1, r0, r1, m0, m1, s0, s1;
    x0.f = f[2*p]; x1.f = f[2*p+1];
    H.u[p] = (x0.u >> 16) | (x1.u & 0xffff0000u);
    h0.u = x0.u & 0xffff0000u; h1.u = x1.u & 0xffff0000u;
    r0.f = x0.f - h0.f;        r1.f = x1.f - h1.f;
    M.u[p] = (r0.u >> 16) | (r1.u & 0xffff0000u);
    m0.u = r0.u & 0xffff0000u; m1.u = r1.u & 0xffff0000u;
    s0.f = r0.f - m0.f;        s1.f = r1.f - m1.f;
    L.u[p] = (s0.u >> 16) | (s1.u & 0xffff0000u);
  }
  hi = H.v; md = M.v; lo = L.v;
}

// ------ split+transpose weights: W[512][512] -> Wt_{h,m,l}[n][k] --------------
__global__ __launch_bounds__(256) void split_w_t3(const float* __restrict__ W,
    unsigned short* __restrict__ Th, unsigned short* __restrict__ Tm,
    unsigned short* __restrict__ Tl)
{
  __shared__ float T[64][65];
  int k0 = blockIdx.x * 64, n0 = blockIdx.y * 64;
  int tid = threadIdx.x;
  int r = tid >> 4, c4 = (tid & 15) << 2;
#pragma unroll
  for (int p = 0; p < 4; ++p) {
    int row = r + p * 16;
    float4 v = *(const float4*)&W[(size_t)(k0 + row) * 512 + n0 + c4];
    T[c4 + 0][row] = v.x; T[c4 + 1][row] = v.y;
    T[c4 + 2][row] = v.z; T[c4 + 3][row] = v.w;
  }
  __syncthreads();
  int nr = tid >> 2, kc = (tid & 3) << 4;
#pragma unroll
  for (int u = 0; u < 16; ++u) {
    unsigned short hb, mb, lb;
    split3_1(T[nr][kc + u], hb, mb, lb);
    size_t o = (size_t)(n0 + nr) * 512 + k0 + kc + u;
    Th[o] = hb; Tm[o] = mb; Tl[o] = lb;
  }
}

// ------ GEMM1: A fp32 in-reg split, dbuf BK=32; writes y1 as 3 bf16 planes ----
__global__ __launch_bounds__(256, 2) void gemm_split3(
    const float* __restrict__ A, const unsigned short* __restrict__ Bth,
    const unsigned short* __restrict__ Btm, const unsigned short* __restrict__ Btl,
    const float* __restrict__ bias,
    unsigned short* __restrict__ Yh, unsigned short* __restrict__ Ym,
    unsigned short* __restrict__ Yl, float* __restrict__ partial)
{
  __shared__ char smem[81920];   // 2 x (sA 16K + 3x8K B)
  const int tid = threadIdx.x;
  const int w = tid >> 6, lane = tid & 63;
  const int bm = blockIdx.x * 128, bn = blockIdx.y * 128;
  const int fr = lane & 15, fg = lane >> 4;
  const int arow = tid >> 3, acb = (tid & 7) << 4;
  const int brow = tid >> 2, bcb = (tid & 3) << 4;

  f32x4 acc[2][8];
#pragma unroll
  for (int mi = 0; mi < 2; ++mi)
#pragma unroll
    for (int ni = 0; ni < 8; ++ni) acc[mi][ni] = (f32x4){0.f, 0.f, 0.f, 0.f};

  auto STAGE = [&](int buf, int ktf) {
    float* sA = (float*)(smem + buf * 40960);
    unsigned short* sBh = (unsigned short*)(smem + buf * 40960 + 16384);
    unsigned short* sBm = sBh + 4096;
    unsigned short* sBl = sBm + 4096;
#pragma unroll
    for (int p = 0; p < 4; ++p) {
      int row = arow + p * 32;
      int cb = acb ^ ((row & 7) << 4);
      gload_lds16f(&A[(size_t)(bm + row) * 512 + ktf + (cb >> 2)],
                   &sA[row * 32 + (acb >> 2)]);
    }
#pragma unroll
    for (int p = 0; p < 2; ++p) {
      int row = brow + p * 64;
      int cb = bcb ^ (((row >> 1) & 3) << 4);
      int so = row * 32 + (bcb >> 1);
      gload_lds16(&Bth[(size_t)(bn + row) * 512 + ktf + (cb >> 1)], &sBh[so]);
      gload_lds16(&Btm[(size_t)(bn + row) * 512 + ktf + (cb >> 1)], &sBm[so]);
      gload_lds16(&Btl[(size_t)(bn + row) * 512 + ktf + (cb >> 1)], &sBl[so]);
    }
  };

  STAGE(0, 0);
  __syncthreads();
  for (int it = 0; it < 16; ++it) {
    int cur = it & 1;
    if (it + 1 < 16) STAGE(cur ^ 1, (it + 1) * 32);
    float* sA = (float*)(smem + cur * 40960);
    unsigned short* sBh = (unsigned short*)(smem + cur * 40960 + 16384);
    unsigned short* sBm = sBh + 4096;
    unsigned short* sBl = sBm + 4096;
    bf16x8 ah[2], am[2], al[2];
#pragma unroll
    for (int mi = 0; mi < 2; ++mi) {
      int row = w * 32 + mi * 16 + fr;
      int swz = (row & 7) << 4;
      const char* rb = (const char*)(sA + row * 32);
      f32x4 f0 = *(const f32x4*)(rb + ((fg * 32) ^ swz));
      f32x4 f1 = *(const f32x4*)(rb + ((fg * 32 + 16) ^ swz));
      split3_8(f0, f1, ah[mi], am[mi], al[mi]);
    }
#pragma unroll
    for (int ni = 0; ni < 8; ++ni) {
      int row = ni * 16 + fr;
      int off = row * 32 + (((fg * 16) ^ (((row >> 1) & 3) << 4)) >> 1);
      bf16x8 bh  = *(const bf16x8*)&sBh[off];
      bf16x8 bmf = *(const bf16x8*)&sBm[off];
      bf16x8 blf = *(const bf16x8*)&sBl[off];
#pragma unroll
      for (int mi = 0; mi < 2; ++mi) {
        acc[mi][ni] = __builtin_amdgcn_mfma_f32_16x16x32_bf16(al[mi], bh,  acc[mi][ni], 0, 0, 0);
        acc[mi][ni] = __builtin_amdgcn_mfma_f32_16x16x32_bf16(am[mi], bmf, acc[mi][ni], 0, 0, 0);
        acc[mi][ni] = __builtin_amdgcn_mfma_f32_16x16x32_bf16(ah[mi], blf, acc[mi][ni], 0, 0, 0);
        acc[mi][ni] = __builtin_amdgcn_mfma_f32_16x16x32_bf16(am[mi], bh,  acc[mi][ni], 0, 0, 0);
        acc[mi][ni] = __builtin_amdgcn_mfma_f32_16x16x32_bf16(ah[mi], bmf, acc[mi][ni], 0, 0, 0);
        acc[mi][ni] = __builtin_amdgcn_mfma_f32_16x16x32_bf16(ah[mi], bh,  acc[mi][ni], 0, 0, 0);
      }
    }
    __syncthreads();
  }

  // epilogue: write y1 as exact 3-plane split + BN column partials
  float ssv[8], qqv[8];
#pragma unroll
  for (int ni = 0; ni < 8; ++ni) {
    float bno = bias[bn + ni * 16 + fr];
    float s = 0.f, q = 0.f;
#pragma unroll
    for (int mi = 0; mi < 2; ++mi) {
      int row = bm + w * 32 + mi * 16 + fg * 4;
      int col = bn + ni * 16 + fr;
#pragma unroll
      for (int r = 0; r < 4; ++r) {
        float v = acc[mi][ni][r] + bno;
        unsigned short hb, mb, lb;
        split3_1(v, hb, mb, lb);
        size_t o = (size_t)(row + r) * 512 + col;
        Yh[o] = hb; Ym[o] = mb; Yl[o] = lb;
        s += v; q += v * v;
      }
    }
    s += __shfl_xor(s, 16); s += __shfl_xor(s, 32);
    q += __shfl_xor(q, 16); q += __shfl_xor(q, 32);
    ssv[ni] = s; qqv[ni] = q;
  }
  float* ps = (float*)smem;
  if (fg == 0) {
#pragma unroll
    for (int ni = 0; ni < 8; ++ni) {
      ps[((w * 2 + 0) * 8 + ni) * 16 + fr] = ssv[ni];
      ps[((w * 2 + 1) * 8 + ni) * 16 + fr] = qqv[ni];
    }
  }
  __syncthreads();
  if ((w & 1) == 0) {
    int p = w >> 1;
#pragma unroll
    for (int k = 0; k < 4; ++k) {
      int idx = k * 64 + lane;
      int part = idx >> 7;
      int rem = idx & 127;
      int ni = rem >> 4, fr2 = rem & 15;
      float v = ps[(((2 * p) * 2 + part) * 8 + ni) * 16 + fr2]
              + ps[(((2 * p + 1) * 2 + part) * 8 + ni) * 16 + fr2];
      int slot = blockIdx.x * 2 + p;
      partial[(size_t)(slot * 2 + part) * 512 + bn + ni * 16 + fr2] = v;
    }
  }
}

// ------ GEMM2: pre-split A planes, single-buffered 48KB, no in-loop split -----
__global__ __launch_bounds__(256, 3) void gemm_presplit3(
    const unsigned short* __restrict__ Ah, const unsigned short* __restrict__ Am,
    const unsigned short* __restrict__ Al,
    const unsigned short* __restrict__ Bth, const unsigned short* __restrict__ Btm,
    const unsigned short* __restrict__ Btl,
    const float* __restrict__ bias, float* __restrict__ C, float* __restrict__ partial)
{
  __shared__ unsigned short sm[6 * 4096];   // 48KB: Ah Am Al Bh Bm Bl
  const int tid = threadIdx.x;
  const int w = tid >> 6, lane = tid & 63;
  const int bm = blockIdx.x * 128, bn = blockIdx.y * 128;
  const int fr = lane & 15, fg = lane >> 4;
  const int brow = tid >> 2, bcb = (tid & 3) << 4;

  f32x4 acc[2][8];
#pragma unroll
  for (int mi = 0; mi < 2; ++mi)
#pragma unroll
    for (int ni = 0; ni < 8; ++ni) acc[mi][ni] = (f32x4){0.f, 0.f, 0.f, 0.f};

  for (int kt = 0; kt < 512; kt += 32) {
#pragma unroll
    for (int p = 0; p < 2; ++p) {
      int row = brow + p * 64;
      int cb = bcb ^ (((row >> 1) & 3) << 4);
      int so = row * 32 + (bcb >> 1);
      size_t ga = (size_t)(bm + row) * 512 + kt + (cb >> 1);
      size_t gb = (size_t)(bn + row) * 512 + kt + (cb >> 1);
      gload_lds16(&Ah[ga],  &sm[0 * 4096 + so]);
      gload_lds16(&Am[ga],  &sm[1 * 4096 + so]);
      gload_lds16(&Al[ga],  &sm[2 * 4096 + so]);
      gload_lds16(&Bth[gb], &sm[3 * 4096 + so]);
      gload_lds16(&Btm[gb], &sm[4 * 4096 + so]);
      gload_lds16(&Btl[gb], &sm[5 * 4096 + so]);
    }
    __syncthreads();
    bf16x8 ah[2], am[2], al[2];
#pragma unroll
    for (int mi = 0; mi < 2; ++mi) {
      int row = w * 32 + mi * 16 + fr;
      int off = row * 32 + (((fg * 16) ^ (((row >> 1) & 3) << 4)) >> 1);
      ah[mi] = *(const bf16x8*)&sm[0 * 4096 + off];
      am[mi] = *(const bf16x8*)&sm[1 * 4096 + off];
      al[mi] = *(const bf16x8*)&sm[2 * 4096 + off];
    }
#pragma unroll
    for (int ni = 0; ni < 8; ++ni) {
      int row = ni * 16 + fr;
      int off = row * 32 + (((fg * 16) ^ (((row >> 1) & 3) << 4)) >> 1);
      bf16x8 bh  = *(const bf16x8*)&sm[3 * 4096 + off];
      bf16x8 bmf = *(const bf16x8*)&sm[4 * 4096 + off];
      bf16x8 blf = *(const bf16x8*)&sm[5 * 4096 + off];
#pragma unroll
      for (int mi = 0; mi < 2; ++mi) {
        acc[mi][ni] = __builtin_amdgcn_mfma_f32_16x16x32_bf16(al[mi], bh,  acc[mi][ni], 0, 0, 0);
        acc[mi][ni] = __builtin_amdgcn_mfma_f32_16x16x32_bf16(am[mi], bmf, acc[mi][ni], 0, 0, 0);
        acc[mi][ni] = __builtin_amdgcn_mfma_f32_16x16x32_bf16(ah[mi], blf, acc[mi][ni], 0, 0, 0);
        acc[mi][ni] = __builtin_amdgcn_mfma_f32_16x16x32_bf16(am[mi], bh,  acc[mi][ni], 0, 0, 0);
        acc[mi][ni] = __builtin_amdgcn_mfma_f32_16x16x32_bf16(ah[mi], bmf, acc[mi][ni], 0, 0, 0);
        acc[mi][ni] = __builtin_amdgcn_mfma_f32_16x16x32_bf16(ah[mi], bh,  acc[mi][ni], 0, 0, 0);
      }
    }
    __syncthreads();
  }

  float ssv[8], qqv[8];
#pragma unroll
  for (int ni = 0; ni < 8; ++ni) {
    float bno = bias[bn + ni * 16 + fr];
    float s = 0.f, q = 0.f;
#pragma unroll
    for (int mi = 0; mi < 2; ++mi) {
      int row = bm + w * 32 + mi * 16 + fg * 4;
      int col = bn + ni * 16 + fr;
#pragma unroll
      for (int r = 0; r < 4; ++r) {
        float v = acc[mi][ni][r] + bno;
        C[(size_t)(row + r) * 512 + col] = v;
        s += v; q += v * v;
      }
    }
    s += __shfl_xor(s, 16); s += __shfl_xor(s, 32);
    q += __shfl_xor(q, 16); q += __shfl_xor(q, 32);
    ssv[ni] = s; qqv[ni] = q;
  }
  float* ps = (float*)sm;
  if (fg == 0) {
#pragma unroll
    for (int ni = 0; ni < 8; ++ni) {
      ps[((w * 2 + 0) * 8 + ni) * 16 + fr] = ssv[ni];
      ps[((w * 2 + 1) * 8 + ni) * 16 + fr] = qqv[ni];
    }
  }
  __syncthreads();
  if ((w & 1) == 0) {
    int p = w >> 1;
#pragma unroll
    for (int k = 0; k < 4; ++k) {
      int idx = k * 64 + lane;
      int part = idx >> 7;
      int rem = idx & 127;
      int ni = rem >> 4, fr2 = rem & 15;
      float v = ps[(((2 * p) * 2 + part) * 8 + ni) * 16 + fr2]
              + ps[(((2 * p + 1) * 2 + part) * 8 + ni) * 16 + fr2];
      int slot = blockIdx.x * 2 + p;
      partial[(size_t)(slot * 2 + part) * 512 + bn + ni * 16 + fr2] = v;
    }
  }
}

// ------ BN reduce stage 1 --------
__global__ __launch_bounds__(256) void bn_reduce1(
    const float* __restrict__ partial, float* __restrict__ partial2, int nslot)
{
  int g = blockIdx.x, p = blockIdx.y;
  int per = nslot >> 4;
  int t = threadIdx.x;
#pragma unroll
  for (int cc = 0; cc < 2; ++cc) {
    int c = t + cc * 256;
    float s = 0.f;
    for (int s0 = 0; s0 < per; ++s0) {
      int slot = g * per + s0;
      s += partial[(size_t)(slot * 2 + p) * 512 + c];
    }
    partial2[(size_t)(g * 2 + p) * 512 + c] = s;
  }
}

__global__ void bn_finalize(
    const float* __restrict__ partial2, const float* __restrict__ g,
    const float* __restrict__ beta, float* __restrict__ scale,
    float* __restrict__ shift, int rows)
{
  int c = blockIdx.x * blockDim.x + threadIdx.x;
  if (c >= 512) return;
  float s = 0, s2 = 0;
  for (int b = 0; b < 16; ++b) {
    s  += partial2[(size_t)(b * 2 + 0) * 512 + c];
    s2 += partial2[(size_t)(b * 2 + 1) * 512 + c];
  }
  float m = s / rows;
  float v = s2 / rows - m * m;
  if (v < 0) v = 0;
  float sc = g[c] / sqrtf(v + 1e-5f);
  scale[c] = sc;
  shift[c] = beta[c] - m * sc;
}

// BN+swish on exact 3-plane y1, re-split in place (bit-identical to fp32 path)
__global__ void bn_swish_split3(
    unsigned short* __restrict__ Ph, unsigned short* __restrict__ Pm,
    unsigned short* __restrict__ Pl,
    const float* __restrict__ scale, const float* __restrict__ shift, int total8)
{
  int i = blockIdx.x * blockDim.x + threadIdx.x;
  if (i >= total8) return;
  size_t base = (size_t)i * 8;
  ushort4 h0 = *(ushort4*)&Ph[base], h1 = *(ushort4*)&Ph[base + 4];
  ushort4 m0 = *(ushort4*)&Pm[base], m1 = *(ushort4*)&Pm[base + 4];
  ushort4 l0 = *(ushort4*)&Pl[base], l1 = *(ushort4*)&Pl[base + 4];
  int c = (int)(base & 511);
  unsigned short hs[8] = {h0.x, h0.y, h0.z, h0.w, h1.x, h1.y, h1.z, h1.w};
  unsigned short ms[8] = {m0.x, m0.y, m0.z, m0.w, m1.x, m1.y, m1.z, m1.w};
  unsigned short ls[8] = {l0.x, l0.y, l0.z, l0.w, l1.x, l1.y, l1.z, l1.w};
  f32x4 va, vb;
#pragma unroll
  for (int u = 0; u < 8; ++u) {
    float v = (bf2f(hs[u]) + bf2f(ms[u])) + bf2f(ls[u]);   // exact reconstruction
    float z = v * scale[c + u] + shift[c + u];
    float sw = z / (1.f + expf(-z));
    if (u < 4) va[u] = sw; else vb[u - 4] = sw;
  }
  bf16x8 H, M, L;
  split3_8(va, vb, H, M, L);
  union { bf16x8 v; ushort4 q[2]; } uH, uM, uL;
  uH.v = H; uM.v = M; uL.v = L;
  *(ushort4*)&Ph[base] = uH.q[0]; *(ushort4*)&Ph[base + 4] = uH.q[1];
  *(ushort4*)&Pm[base] = uM.q[0]; *(ushort4*)&Pm[base + 4] = uM.q[1];
  *(ushort4*)&Pl[base] = uL.q[0]; *(ushort4*)&Pl[base + 4] = uL.q[1];
}

__global__ void bn_swish(
    const float* __restrict__ Y, const float* __restrict__ scale,
    const float* __restrict__ shift, float* __restrict__ H, int total4)
{
  int i = blockIdx.x * blockDim.x + threadIdx.x;
  if (i >= total4) return;
  float4 y = ((const float4*)Y)[i];
  int c = (i * 4) & 511;
  float z;
  float4 o;
  z = y.x * scale[c + 0] + shift[c + 0]; o.x = z / (1.f + expf(-z));
  z = y.y * scale[c + 1] + shift[c + 1]; o.y = z / (1.f + expf(-z));
  z = y.z * scale[c + 2] + shift[c + 2]; o.z = z / (1.f + expf(-z));
  z = y.w * scale[c + 3] + shift[c + 3]; o.w = z / (1.f + expf(-z));
  ((float4*)H)[i] = o;
}

// ---------------- positive-label compaction: 3-kernel scan ----------------
__global__ __launch_bounds__(1024) void pos_count(const int* __restrict__ lbl, int n,
                                                  int* __restrict__ cnt,
                                                  int* __restrict__ pos, int P)
{
  int b = blockIdx.x, tid = threadIdx.x;
  int i = b * 1024 + tid;
  if (i < P) pos[i] = 0;
  int pred = (i < n) && (lbl[i] > 0);
  unsigned long long m = __ballot(pred);
  __shared__ int ws[16];
  if ((tid & 63) == 0) ws[tid >> 6] = __popcll(m);
  __syncthreads();
  if (tid == 0) { int s = 0; for (int k = 0; k < 16; ++k) s += ws[k]; cnt[b] = s; }
}

__global__ void pos_prefix(int* __restrict__ cnt, int nb)
{
  if (threadIdx.x == 0) {
    int s = 0;
    for (int b = 0; b < nb; ++b) { int c = cnt[b]; cnt[b] = s; s += c; }
  }
}

__global__ __launch_bounds__(1024) void pos_scatter(const int* __restrict__ lbl, int n,
                                                    const int* __restrict__ cntp,
                                                    int* __restrict__ pos, int P)
{
  int b = blockIdx.x, tid = threadIdx.x;
  int i = b * 1024 + tid;
  int pred = (i < n) && (lbl[i] > 0);
  unsigned long long m = __ballot(pred);
  __shared__ int ws[16];
  int wid = tid >> 6, lane = tid & 63;
  if (lane == 0) ws[wid] = __popcll(m);
  __syncthreads();
  int wbase = 0;
  for (int w2 = 0; w2 < wid; ++w2) wbase += ws[w2];
  int rank = cntp[b] + wbase + __popcll(m & ((1ull << lane) - 1ull));
  if (pred && rank < P) pos[rank] = i;
}

// ---------------- gather positives + sq norms + bf16 copy ----------------
__global__ void gather_sq(const float* __restrict__ H, const int* __restrict__ pos,
                          float* __restrict__ X, unsigned short* __restrict__ Xh,
                          float* __restrict__ sq)
{
  int r = blockIdx.x, t = threadIdx.x;  // 128 threads
  int src = pos[r];
  float4 v = *(const float4*)&H[src * 512 + t * 4];
  *(float4*)&X[r * 512 + t * 4] = v;
  ushort4 hv;
  hv.x = f2bf(v.x); hv.y = f2bf(v.y); hv.z = f2bf(v.z); hv.w = f2bf(v.w);
  *(ushort4*)&Xh[r * 512 + t * 4] = hv;
  float s = v.x * v.x + v.y * v.y + v.z * v.z + v.w * v.w;
#pragma unroll
  for (int off = 32; off > 0; off >>= 1) s += __shfl_down(s, off);
  __shared__ float red[2];
  if ((t & 63) == 0) red[t >> 6] = s;
  __syncthreads();
  if (t == 0) sq[r] = red[0] + red[1];
}

// ------ symmetric Gram: one block per upper-tri 128x128 tile, dual scan -------
__global__ __launch_bounds__(256, 4) void gram_sym(
    const unsigned short* __restrict__ Xh, const float* __restrict__ sq,
    float* __restrict__ p8v, int* __restrict__ p8j)
{
  __shared__ char smem[33792];
  __shared__ float sqi_l[128], sqj_l[128];
  unsigned short* Ah = (unsigned short*)smem;
  unsigned short* Bh = (unsigned short*)(smem + 16384);
  float (*dl)[64][33] = (float (*)[64][33])(void*)smem;
  float* mv = (float*)smem;
  int*   mj = (int*)(smem + 8192);

  const int tid = threadIdx.x;
  const int w = tid >> 6, lane = tid & 63;
  const int wr = w >> 1, wc = w & 1;
  const int fr = lane & 15, fg = lane >> 4;
  const int srow = tid >> 3;
  const int scb  = (tid & 7) << 4;

  int t = blockIdx.x;
  int a = (int)(64.5f - sqrtf(64.5f * 64.5f - 2.0f * (float)t));
  if (a < 0) a = 0;
  while (a > 0 && (a * (129 - a)) / 2 > t) --a;
  while (((a + 1) * (128 - a)) / 2 <= t) ++a;
  int b = a + (t - (a * (129 - a)) / 2);
  const int ai0 = a * 128, bj0 = b * 128;

  if (tid < 128) { sqi_l[tid] = sq[ai0 + tid]; sqj_l[tid] = sq[bj0 + tid]; }

  f32x4 acc[4][4];
#pragma unroll
  for (int mi = 0; mi < 4; ++mi)
#pragma unroll
    for (int ni = 0; ni < 4; ++ni) acc[mi][ni] = (f32x4){0.f, 0.f, 0.f, 0.f};

  for (int kt = 0; kt < 512; kt += 64) {
#pragma unroll
    for (int it = 0; it < 4; ++it) {
      int row = srow + it * 32;
      int cb = scb ^ ((row & 7) << 4);
      gload_lds16(&Xh[(size_t)(ai0 + row) * 512 + kt + (cb >> 1)],
                  &Ah[row * 64 + (scb >> 1)]);
      gload_lds16(&Xh[(size_t)(bj0 + row) * 512 + kt + (cb >> 1)],
                  &Bh[row * 64 + (scb >> 1)]);
    }
    __syncthreads();
#pragma unroll
    for (int ks = 0; ks < 2; ++ks) {
      bf16x8 af[4], bfr[4];
      int kb = ks * 64 + fg * 16;
#pragma unroll
      for (int mi = 0; mi < 4; ++mi) {
        int row = wr * 64 + mi * 16 + fr;
        af[mi] = *(const bf16x8*)&Ah[row * 64 + ((kb ^ ((row & 7) << 4)) >> 1)];
      }
#pragma unroll
      for (int ni = 0; ni < 4; ++ni) {
        int row = wc * 64 + ni * 16 + fr;
        bfr[ni] = *(const bf16x8*)&Bh[row * 64 + ((kb ^ ((row & 7) << 4)) >> 1)];
      }
#pragma unroll
      for (int mi = 0; mi < 4; ++mi)
#pragma unroll
        for (int ni = 0; ni < 4; ++ni)
          acc[mi][ni] = __builtin_amdgcn_mfma_f32_16x16x32_bf16(
              af[mi], bfr[ni], acc[mi][ni], 0, 0, 0);
    }
    __syncthreads();
  }

  float t8[8]; int j8[8];
#pragma unroll
  for (int q = 0; q < 8; ++q) { t8[q] = NEG_INF; j8[q] = 0x7fffffff; }

#pragma unroll
  for (int qp = 0; qp < 2; ++qp) {
#pragma unroll
    for (int qh = 0; qh < 2; ++qh) {
      int qn = qp * 2 + qh;
      float sqv = sqj_l[wc * 64 + qn * 16 + fr];
#pragma unroll
      for (int mi = 0; mi < 4; ++mi)
#pragma unroll
        for (int r = 0; r < 4; ++r)
          dl[w][mi * 16 + fg * 4 + r][qh * 16 + fr] = 2.0f * acc[mi][qn][r] - sqv;
    }
    __syncthreads();
    int jbase = bj0 + wc * 64 + qp * 32;
    for (int c = 0; c < 32; ++c) {
      float v = dl[w][lane][c];
      if (v > t8[7]) {
        t8[7] = v; j8[7] = jbase + c;
#pragma unroll
        for (int q = 7; q > 0; --q)
          if (t8[q] > t8[q - 1]) {
            float tv = t8[q]; t8[q] = t8[q - 1]; t8[q - 1] = tv;
            int tj = j8[q]; j8[q] = j8[q - 1]; j8[q - 1] = tj;
          }
      }
    }
    __syncthreads();
  }
#pragma unroll
  for (int q = 0; q < 8; ++q) {
    mv[(w * 64 + lane) * 8 + q] = t8[q];
    mj[(w * 64 + lane) * 8 + q] = j8[q];
  }
  __syncthreads();
  if ((w & 1) == 0) {
    int row = ai0 + (w >> 1) * 64 + lane;
    const float* v0 = &mv[(w * 64 + lane) * 8];
    const int*   c0 = &mj[(w * 64 + lane) * 8];
    const float* v1 = &mv[((w + 1) * 64 + lane) * 8];
    const int*   c1 = &mj[((w + 1) * 64 + lane) * 8];
    size_t ob = ((size_t)row * 64 + b) * 8;
    int h0 = 0, h1 = 0;
    for (int k = 0; k < 8; ++k) {
      float a0 = (h0 < 8) ? v0[h0] : NEG_INF;
      float a1 = (h1 < 8) ? v1[h1] : NEG_INF;
      int   b0 = (h0 < 8) ? c0[h0] : 0x7fffffff;
      int   b1 = (h1 < 8) ? c1[h1] : 0x7fffffff;
      bool take0 = (a0 > a1) || (a0 == a1 && b0 < b1);
      p8v[ob + k] = take0 ? a0 : a1;
      p8j[ob + k] = take0 ? b0 : b1;
      if (take0) ++h0; else ++h1;
    }
  }

  if (a != b) {
    __syncthreads();
#pragma unroll
    for (int q = 0; q < 8; ++q) { t8[q] = NEG_INF; j8[q] = 0x7fffffff; }
#pragma unroll
    for (int mp = 0; mp < 2; ++mp) {
#pragma unroll
      for (int mh = 0; mh < 2; ++mh) {
        int mi = mp * 2 + mh;
        f32x4 sv = *(const f32x4*)&sqi_l[wr * 64 + mi * 16 + fg * 4];
#pragma unroll
        for (int ni = 0; ni < 4; ++ni)
#pragma unroll
          for (int r = 0; r < 4; ++r)
            dl[w][ni * 16 + fr][mh * 16 + fg * 4 + r] = 2.0f * acc[mi][ni][r] - sv[r];
      }
      __syncthreads();
      int ibase = ai0 + wr * 64 + mp * 32;
      for (int c = 0; c < 32; ++c) {
        float v = dl[w][lane][c];
        if (v > t8[7]) {
          t8[7] = v; j8[7] = ibase + c;
#pragma unroll
          for (int q = 7; q > 0; --q)
            if (t8[q] > t8[q - 1]) {
              float tv = t8[q]; t8[q] = t8[q - 1]; t8[q - 1] = tv;
              int tj = j8[q]; j8[q] = j8[q - 1]; j8[q - 1] = tj;
            }
        }
      }
      __syncthreads();
    }
#pragma unroll
    for (int q = 0; q < 8; ++q) {
      mv[(w * 64 + lane) * 8 + q] = t8[q];
      mj[(w * 64 + lane) * 8 + q] = j8[q];
    }
    __syncthreads();
    if (wr == 0) {
      int row = bj0 + wc * 64 + lane;
      const float* v0 = &mv[(w * 64 + lane) * 8];
      const int*   c0 = &mj[(w * 64 + lane) * 8];
      const float* v1 = &mv[((w + 2) * 64 + lane) * 8];
      const int*   c1 = &mj[((w + 2) * 64 + lane) * 8];
      size_t ob = ((size_t)row * 64 + a) * 8;
      int h0 = 0, h1 = 0;
      for (int k = 0; k < 8; ++k) {
        float a0 = (h0 < 8) ? v0[h0] : NEG_INF;
        float a1 = (h1 < 8) ? v1[h1] : NEG_INF;
        int   b0 = (h0 < 8) ? c0[h0] : 0x7fffffff;
        int   b1 = (h1 < 8) ? c1[h1] : 0x7fffffff;
        bool take0 = (a0 > a1) || (a0 == a1 && b0 < b1);
        p8v[ob + k] = take0 ? a0 : a1;
        p8j[ob + k] = take0 ? b0 : b1;
        if (take0) ++h0; else ++h1;
      }
    }
  }
}

// ------- wave-parallel merge: 64 sorted lists (one per lane) -> top-8 ---------
__global__ __launch_bounds__(256) void merge8w(const float* __restrict__ p8v,
                                               const int* __restrict__ p8j,
                                               int* __restrict__ cand, int P)
{
  int row = blockIdx.x * 4 + (threadIdx.x >> 6);
  int lane = threadIdx.x & 63;
  if (row >= P) return;
  const float* v = p8v + (size_t)row * 512 + lane * 8;
  const int* j = p8j + (size_t)row * 512 + lane * 8;
  float vv[8]; int jj[8];
#pragma unroll
  for (int q = 0; q < 8; ++q) { vv[q] = v[q]; jj[q] = j[q]; }
  for (int k = 0; k < 8; ++k) {
    float cv = vv[0]; int cj = jj[0];
#pragma unroll
    for (int off = 1; off < 64; off <<= 1) {
      float ov = __shfl_xor(cv, off);
      int oj = __shfl_xor(cj, off);
      if (ov > cv || (ov == cv && oj < cj)) { cv = ov; cj = oj; }
    }
    if (lane == 0) cand[row * 8 + k] = cj;
    if (jj[0] == cj) {
#pragma unroll
      for (int q = 0; q < 7; ++q) { vv[q] = vv[q + 1]; jj[q] = jj[q + 1]; }
      vv[7] = NEG_INF; jj[7] = 0x7fffffff;
    }
  }
}

// ---------------- exact fp32 rescore of 8 candidates -> top-3 --------------
__global__ __launch_bounds__(64) void rescore(
    const float* __restrict__ X, const float* __restrict__ sq,
    const int* __restrict__ cand, int* __restrict__ idx3)
{
  int i = blockIdx.x;
  int lane = threadIdx.x;
  f32x4 x0 = *(const f32x4*)&X[(size_t)i * 512 + lane * 8];
  f32x4 x1 = *(const f32x4*)&X[(size_t)i * 512 + lane * 8 + 4];
  float d[8]; int cj[8];
#pragma unroll
  for (int c = 0; c < 8; ++c) {
    int j = cand[i * 8 + c];
    cj[c] = j;
    f32x4 y0 = *(const f32x4*)&X[(size_t)j * 512 + lane * 8];
    f32x4 y1 = *(const f32x4*)&X[(size_t)j * 512 + lane * 8 + 4];
    float p = x0.x * y0.x + x0.y * y0.y + x0.z * y0.z + x0.w * y0.w
            + x1.x * y1.x + x1.y * y1.y + x1.z * y1.z + x1.w * y1.w;
#pragma unroll
    for (int off = 32; off > 0; off >>= 1) p += __shfl_xor(p, off);
    d[c] = 2.0f * p - sq[i] - sq[j];
  }
  if (lane == 0) {
    for (int k = 0; k < 3; ++k) {
      int b = 0;
#pragma unroll
      for (int c = 1; c < 8; ++c)
        if (d[c] > d[b] || (d[c] == d[b] && cj[c] < cj[b])) b = c;
      idx3[i * 3 + k] = cj[b];
      d[b] = NEG_INF; cj[b] = 0x7fffffff;
    }
  }
}

// ---------------- SMOTE lerp rows: one block per i, 3 outputs -------------
__global__ void make_newfea(const float* __restrict__ X, const int* __restrict__ idx3,
                            const float* __restrict__ lw, float* __restrict__ out)
{
  int i = blockIdx.x;
  int t = threadIdx.x;          // 128 threads
  int ai = idx3[i * 3 + 0];
  float4 av = *(const float4*)&X[(size_t)ai * 512 + t * 4];
  *(float4*)&out[(size_t)(i * 3) * 512 + t * 4] = av;   // k=0: b==a -> a exactly
#pragma unroll
  for (int k = 1; k < 3; ++k) {
    int bi = idx3[i * 3 + k];
    float w = lw[i * 3 + k];
    float4 bv = *(const float4*)&X[(size_t)bi * 512 + t * 4];
    float4 o;
    o.x = av.x + w * (bv.x - av.x);
    o.y = av.y + w * (bv.y - av.y);
    o.z = av.z + w * (bv.z - av.z);
    o.w = av.w + w * (bv.w - av.w);
    *(float4*)&out[(size_t)(i * 3 + k) * 512 + t * 4] = o;
  }
}

__global__ void write_lbl(const int* __restrict__ lbl, float* __restrict__ out,
                          int n_in, int n_total)
{
  int i = blockIdx.x * blockDim.x + threadIdx.x;
  if (i < n_total) out[i] = (i < n_in) ? (float)lbl[i] : 1.0f;
}

// ---------------- launch ----------------
extern "C" void kernel_launch(void* const* d_in, const int* in_sizes, int n_in,
                              void* d_out, int out_size, void* d_ws, size_t ws_size,
                              hipStream_t stream)
{
  const float* fea   = (const float*)d_in[0];
  const int*   lbl   = (const int*)d_in[1];
  const float* W1    = (const float*)d_in[2];
  const float* b1    = (const float*)d_in[3];
  const float* g1    = (const float*)d_in[4];
  const float* beta1 = (const float*)d_in[5];
  const float* W2    = (const float*)d_in[6];
  const float* b2    = (const float*)d_in[7];
  const float* g2    = (const float*)d_in[8];
  const float* beta2 = (const float*)d_in[9];
  const float* lerp_w = (const float*)d_in[10];

  int bs = in_sizes[0] / 512;       // 32768
  int P  = in_sizes[10] / 3;        // 8192
  int n_total = bs + 3 * P;         // 57344

  float* out_f = (float*)d_out;
  float* Hout = out_f;
  float* newfea = out_f + (size_t)bs * 512;
  float* lbl_out = out_f + (size_t)n_total * 512;

  const size_t MB = 1024 * 1024;
  const size_t KB = 1024;
  char* ws = (char*)d_ws;
  // y1 planes: h,m in ws[0..64MB); l parked in d_out's newfea region (unused until
  // make_newfea, which runs after gemm2).
  unsigned short* A1h = (unsigned short*)ws;                       // 32MB
  unsigned short* A1m = (unsigned short*)(ws + 32 * MB);           // 32MB
  unsigned short* A1l = (unsigned short*)newfea;                   // 32MB of 48MB region
  float* X  = (float*)(ws + 64 * MB);                              // 16MB (after weights dead)
  unsigned short* W1h = (unsigned short*)(ws + 64 * MB);
  unsigned short* W1m = (unsigned short*)(ws + 64 * MB + 512 * KB);
  unsigned short* W1l = (unsigned short*)(ws + 64 * MB + 1024 * KB);
  unsigned short* W2h = (unsigned short*)(ws + 64 * MB + 1536 * KB);
  unsigned short* W2m = (unsigned short*)(ws + 64 * MB + 2048 * KB);
  unsigned short* W2l = (unsigned short*)(ws + 64 * MB + 2560 * KB);
  float* partial = (float*)(ws + 80 * MB);                         // 2MB
  float* scale = (float*)(ws + 82 * MB);
  float* shiftv = scale + 512;
  float* sq = shiftv + 512;
  int* pos = (int*)(sq + 8192);
  int* idx3 = pos + 8192;
  int* cnt = idx3 + 3 * 8192;
  float* partial2 = (float*)(ws + 83 * MB);                        // 64KB
  // overlays in ws[0..64MB) (dead after gemm2):
  unsigned short* Xh = (unsigned short*)ws;                        // 8MB
  float* p8v = (float*)(ws + 8 * MB);                              // 16MB
  int*   p8j = (int*)(ws + 24 * MB);                               // 16MB
  int*   cand = (int*)(ws + 40 * MB);                              // 256KB

  dim3 wgrid(8, 8);
  split_w_t3<<<wgrid, 256, 0, stream>>>(W1, W1h, W1m, W1l);
  split_w_t3<<<wgrid, 256, 0, stream>>>(W2, W2h, W2m, W2l);

  dim3 ggrid(bs / 128, 4);
  int nslot = (bs / 128) * 2;          // 512
  dim3 rgrid(16, 2);
  int total8 = bs * 512 / 8;

  gemm_split3<<<ggrid, 256, 0, stream>>>(fea, W1h, W1m, W1l, b1, A1h, A1m, A1l, partial);
  bn_reduce1<<<rgrid, 256, 0, stream>>>(partial, partial2, nslot);
  bn_finalize<<<2, 256, 0, stream>>>(partial2, g1, beta1, scale, shiftv, bs);
  bn_swish_split3<<<(total8 + 255) / 256, 256, 0, stream>>>(A1h, A1m, A1l, scale, shiftv, total8);

  gemm_presplit3<<<ggrid, 256, 0, stream>>>(A1h, A1m, A1l, W2h, W2m, W2l, b2, Hout, partial);
  bn_reduce1<<<rgrid, 256, 0, stream>>>(partial, partial2, nslot);
  bn_finalize<<<2, 256, 0, stream>>>(partial2, g2, beta2, scale, shiftv, bs);
  bn_swish<<<(bs * 512 / 4 + 255) / 256, 256, 0, stream>>>(Hout, scale, shiftv, Hout, bs * 512 / 4);

  int nb = (bs + 1023) / 1024;         // 32
  pos_count<<<nb, 1024, 0, stream>>>(lbl, bs, cnt, pos, P);
  pos_prefix<<<1, 64, 0, stream>>>(cnt, nb);
  pos_scatter<<<nb, 1024, 0, stream>>>(lbl, bs, cnt, pos, P);
  gather_sq<<<P, 128, 0, stream>>>(Hout, pos, X, Xh, sq);

  int nbk = P / 128;                    // 64
  int ntri = nbk * (nbk + 1) / 2;       // 2080
  gram_sym<<<ntri, 256, 0, stream>>>(Xh, sq, p8v, p8j);
  merge8w<<<(P + 3) / 4, 256, 0, stream>>>(p8v, p8j, cand, P);
  rescore<<<P, 64, 0, stream>>>(X, sq, cand, idx3);

  make_newfea<<<P, 128, 0, stream>>>(X, idx3, lerp_w, newfea);
  write_lbl<<<(n_total + 255) / 256, 256, 0, stream>>>(lbl, lbl_out, bs, n_total);
}

// Round 12
// 470.842 us; speedup vs baseline: 1.0496x; 1.0496x over previous
//
#include <hip/hip_runtime.h>
#include <math.h>

#define NEG_INF -3.402823466e38f

typedef __attribute__((ext_vector_type(8))) short bf16x8;
typedef __attribute__((ext_vector_type(4))) float f32x4;
typedef __attribute__((ext_vector_type(2))) float f32x2;

__device__ __forceinline__ void gload_lds16(const unsigned short* g, unsigned short* l) {
  __builtin_amdgcn_global_load_lds(
      (const __attribute__((address_space(1))) unsigned int*)g,
      (__attribute__((address_space(3))) unsigned int*)l, 16, 0, 0);
}
__device__ __forceinline__ void gload_lds16f(const float* g, float* l) {
  __builtin_amdgcn_global_load_lds(
      (const __attribute__((address_space(1))) unsigned int*)g,
      (__attribute__((address_space(3))) unsigned int*)l, 16, 0, 0);
}

__device__ __forceinline__ unsigned short f2bf(float f) {
  union { float f; unsigned int u; } a; a.f = f;
  unsigned int u = a.u;
  return (unsigned short)((u + 0x7fffu + ((u >> 16) & 1u)) >> 16);
}

// pairwise 3-term truncation split: 8 f32 -> hi/mid/lo bf16x8.
__device__ __forceinline__ void split3_8(f32x4 a, f32x4 b,
                                         bf16x8& hi, bf16x8& md, bf16x8& lo) {
  union { bf16x8 v; unsigned int u[4]; } H, M, L;
  float f[8];
  f[0]=a[0]; f[1]=a[1]; f[2]=a[2]; f[3]=a[3];
  f[4]=b[0]; f[5]=b[1]; f[6]=b[2]; f[7]=b[3];
#pragma unroll
  for (int p = 0; p < 4; ++p) {
    union { float f; unsigned int u; } x0, x1, h0, h1, r0, r1, m0, m1, s0, s1;
    x0.f = f[2*p]; x1.f = f[2*p+1];
    H.u[p] = (x0.u >> 16) | (x1.u & 0xffff0000u);
    h0.u = x0.u & 0xffff0000u; h1.u = x1.u & 0xffff0000u;
    r0.f = x0.f - h0.f;        r1.f = x1.f - h1.f;
    M.u[p] = (r0.u >> 16) | (r1.u & 0xffff0000u);
    m0.u = r0.u & 0xffff0000u; m1.u = r1.u & 0xffff0000u;
    s0.f = r0.f - m0.f;        s1.f = r1.f - m1.f;
    L.u[p] = (s0.u >> 16) | (s1.u & 0xffff0000u);
  }
  hi = H.v; md = M.v; lo = L.v;
}

// ------ split+transpose weights: W[512][512] -> Wt_{h,m,l}[n][k] --------------
__global__ __launch_bounds__(256) void split_w_t3(const float* __restrict__ W,
    unsigned short* __restrict__ Th, unsigned short* __restrict__ Tm,
    unsigned short* __restrict__ Tl)
{
  __shared__ float T[64][65];
  int k0 = blockIdx.x * 64, n0 = blockIdx.y * 64;
  int tid = threadIdx.x;
  int r = tid >> 4, c4 = (tid & 15) << 2;
#pragma unroll
  for (int p = 0; p < 4; ++p) {
    int row = r + p * 16;
    float4 v = *(const float4*)&W[(size_t)(k0 + row) * 512 + n0 + c4];
    T[c4 + 0][row] = v.x; T[c4 + 1][row] = v.y;
    T[c4 + 2][row] = v.z; T[c4 + 3][row] = v.w;
  }
  __syncthreads();
  int nr = tid >> 2, kc = (tid & 3) << 4;
#pragma unroll
  for (int u = 0; u < 16; ++u) {
    union { float f; unsigned int u; } x, h, rr, m, ss;
    x.f = T[nr][kc + u];
    unsigned short hb = (unsigned short)(x.u >> 16);
    h.u = x.u & 0xffff0000u;
    rr.f = x.f - h.f;
    unsigned short mb = (unsigned short)(rr.u >> 16);
    m.u = rr.u & 0xffff0000u;
    ss.f = rr.f - m.f;
    unsigned short lb = (unsigned short)(ss.u >> 16);
    size_t o = (size_t)(n0 + nr) * 512 + k0 + kc + u;
    Th[o] = hb; Tm[o] = mb; Tl[o] = lb;
  }
}

// ------ GEMM: dbuf BK=32, wave = 32 rows x 128 cols (2 splits/iter) -----------
__global__ __launch_bounds__(256, 2) void gemm_split3(
    const float* __restrict__ A, const unsigned short* __restrict__ Bth,
    const unsigned short* __restrict__ Btm, const unsigned short* __restrict__ Btl,
    const float* __restrict__ bias, float* __restrict__ C, float* __restrict__ partial)
{
  __shared__ char smem[81920];   // 2 x (sA 16K + 3x8K B)
  const int tid = threadIdx.x;
  const int w = tid >> 6, lane = tid & 63;
  const int bm = blockIdx.x * 128, bn = blockIdx.y * 128;
  const int fr = lane & 15, fg = lane >> 4;
  const int arow = tid >> 3, acb = (tid & 7) << 4;
  const int brow = tid >> 2, bcb = (tid & 3) << 4;

  f32x4 acc[2][8];
#pragma unroll
  for (int mi = 0; mi < 2; ++mi)
#pragma unroll
    for (int ni = 0; ni < 8; ++ni) acc[mi][ni] = (f32x4){0.f, 0.f, 0.f, 0.f};

  auto STAGE = [&](int buf, int ktf) {
    float* sA = (float*)(smem + buf * 40960);
    unsigned short* sBh = (unsigned short*)(smem + buf * 40960 + 16384);
    unsigned short* sBm = sBh + 4096;
    unsigned short* sBl = sBm + 4096;
#pragma unroll
    for (int p = 0; p < 4; ++p) {
      int row = arow + p * 32;
      int cb = acb ^ ((row & 7) << 4);
      gload_lds16f(&A[(size_t)(bm + row) * 512 + ktf + (cb >> 2)],
                   &sA[row * 32 + (acb >> 2)]);
    }
#pragma unroll
    for (int p = 0; p < 2; ++p) {
      int row = brow + p * 64;
      int cb = bcb ^ (((row >> 1) & 3) << 4);
      int so = row * 32 + (bcb >> 1);
      gload_lds16(&Bth[(size_t)(bn + row) * 512 + ktf + (cb >> 1)], &sBh[so]);
      gload_lds16(&Btm[(size_t)(bn + row) * 512 + ktf + (cb >> 1)], &sBm[so]);
      gload_lds16(&Btl[(size_t)(bn + row) * 512 + ktf + (cb >> 1)], &sBl[so]);
    }
  };

  STAGE(0, 0);
  __syncthreads();
  for (int it = 0; it < 16; ++it) {
    int cur = it & 1;
    if (it + 1 < 16) STAGE(cur ^ 1, (it + 1) * 32);
    float* sA = (float*)(smem + cur * 40960);
    unsigned short* sBh = (unsigned short*)(smem + cur * 40960 + 16384);
    unsigned short* sBm = sBh + 4096;
    unsigned short* sBl = sBm + 4096;
    bf16x8 ah[2], am[2], al[2];
#pragma unroll
    for (int mi = 0; mi < 2; ++mi) {
      int row = w * 32 + mi * 16 + fr;
      int swz = (row & 7) << 4;
      const char* rb = (const char*)(sA + row * 32);
      f32x4 f0 = *(const f32x4*)(rb + ((fg * 32) ^ swz));
      f32x4 f1 = *(const f32x4*)(rb + ((fg * 32 + 16) ^ swz));
      split3_8(f0, f1, ah[mi], am[mi], al[mi]);
    }
#pragma unroll
    for (int ni = 0; ni < 8; ++ni) {
      int row = ni * 16 + fr;
      int off = row * 32 + (((fg * 16) ^ (((row >> 1) & 3) << 4)) >> 1);
      bf16x8 bh  = *(const bf16x8*)&sBh[off];
      bf16x8 bmf = *(const bf16x8*)&sBm[off];
      bf16x8 blf = *(const bf16x8*)&sBl[off];
#pragma unroll
      for (int mi = 0; mi < 2; ++mi) {
        acc[mi][ni] = __builtin_amdgcn_mfma_f32_16x16x32_bf16(al[mi], bh,  acc[mi][ni], 0, 0, 0);
        acc[mi][ni] = __builtin_amdgcn_mfma_f32_16x16x32_bf16(am[mi], bmf, acc[mi][ni], 0, 0, 0);
        acc[mi][ni] = __builtin_amdgcn_mfma_f32_16x16x32_bf16(ah[mi], blf, acc[mi][ni], 0, 0, 0);
        acc[mi][ni] = __builtin_amdgcn_mfma_f32_16x16x32_bf16(am[mi], bh,  acc[mi][ni], 0, 0, 0);
        acc[mi][ni] = __builtin_amdgcn_mfma_f32_16x16x32_bf16(ah[mi], bmf, acc[mi][ni], 0, 0, 0);
        acc[mi][ni] = __builtin_amdgcn_mfma_f32_16x16x32_bf16(ah[mi], bh,  acc[mi][ni], 0, 0, 0);
      }
    }
    __syncthreads();
  }

  float ssv[8], qqv[8];
#pragma unroll
  for (int ni = 0; ni < 8; ++ni) {
    float bno = bias[bn + ni * 16 + fr];
    float s = 0.f, q = 0.f;
#pragma unroll
    for (int mi = 0; mi < 2; ++mi) {
      int row = bm + w * 32 + mi * 16 + fg * 4;
      int col = bn + ni * 16 + fr;
#pragma unroll
      for (int r = 0; r < 4; ++r) {
        float v = acc[mi][ni][r] + bno;
        C[(size_t)(row + r) * 512 + col] = v;
        s += v; q += v * v;
      }
    }
    s += __shfl_xor(s, 16); s += __shfl_xor(s, 32);
    q += __shfl_xor(q, 16); q += __shfl_xor(q, 32);
    ssv[ni] = s; qqv[ni] = q;
  }
  float* ps = (float*)smem;
  if (fg == 0) {
#pragma unroll
    for (int ni = 0; ni < 8; ++ni) {
      ps[((w * 2 + 0) * 8 + ni) * 16 + fr] = ssv[ni];
      ps[((w * 2 + 1) * 8 + ni) * 16 + fr] = qqv[ni];
    }
  }
  __syncthreads();
  if ((w & 1) == 0) {
    int p = w >> 1;
#pragma unroll
    for (int k = 0; k < 4; ++k) {
      int idx = k * 64 + lane;
      int part = idx >> 7;
      int rem = idx & 127;
      int ni = rem >> 4, fr2 = rem & 15;
      float v = ps[(((2 * p) * 2 + part) * 8 + ni) * 16 + fr2]
              + ps[(((2 * p + 1) * 2 + part) * 8 + ni) * 16 + fr2];
      int slot = blockIdx.x * 2 + p;
      partial[(size_t)(slot * 2 + part) * 512 + bn + ni * 16 + fr2] = v;
    }
  }
}

// ------ BN reduce stage 1 --------
__global__ __launch_bounds__(256) void bn_reduce1(
    const float* __restrict__ partial, float* __restrict__ partial2, int nslot)
{
  int g = blockIdx.x, p = blockIdx.y;
  int per = nslot >> 4;
  int t = threadIdx.x;
#pragma unroll
  for (int cc = 0; cc < 2; ++cc) {
    int c = t + cc * 256;
    float s = 0.f;
    for (int s0 = 0; s0 < per; ++s0) {
      int slot = g * per + s0;
      s += partial[(size_t)(slot * 2 + p) * 512 + c];
    }
    partial2[(size_t)(g * 2 + p) * 512 + c] = s;
  }
}

__global__ void bn_finalize(
    const float* __restrict__ partial2, const float* __restrict__ g,
    const float* __restrict__ beta, float* __restrict__ scale,
    float* __restrict__ shift, int rows)
{
  int c = blockIdx.x * blockDim.x + threadIdx.x;
  if (c >= 512) return;
  float s = 0, s2 = 0;
  for (int b = 0; b < 16; ++b) {
    s  += partial2[(size_t)(b * 2 + 0) * 512 + c];
    s2 += partial2[(size_t)(b * 2 + 1) * 512 + c];
  }
  float m = s / rows;
  float v = s2 / rows - m * m;
  if (v < 0) v = 0;
  float sc = g[c] / sqrtf(v + 1e-5f);
  scale[c] = sc;
  shift[c] = beta[c] - m * sc;
}

__global__ void bn_swish(
    const float* __restrict__ Y, const float* __restrict__ scale,
    const float* __restrict__ shift, float* __restrict__ H, int total4)
{
  int i = blockIdx.x * blockDim.x + threadIdx.x;
  if (i >= total4) return;
  float4 y = ((const float4*)Y)[i];
  int c = (i * 4) & 511;
  float z;
  float4 o;
  z = y.x * scale[c + 0] + shift[c + 0]; o.x = z / (1.f + expf(-z));
  z = y.y * scale[c + 1] + shift[c + 1]; o.y = z / (1.f + expf(-z));
  z = y.z * scale[c + 2] + shift[c + 2]; o.z = z / (1.f + expf(-z));
  z = y.w * scale[c + 3] + shift[c + 3]; o.w = z / (1.f + expf(-z));
  ((float4*)H)[i] = o;
}

// ---------------- positive-label compaction: 3-kernel scan ----------------
__global__ __launch_bounds__(1024) void pos_count(const int* __restrict__ lbl, int n,
                                                  int* __restrict__ cnt,
                                                  int* __restrict__ pos, int P)
{
  int b = blockIdx.x, tid = threadIdx.x;
  int i = b * 1024 + tid;
  if (i < P) pos[i] = 0;
  int pred = (i < n) && (lbl[i] > 0);
  unsigned long long m = __ballot(pred);
  __shared__ int ws[16];
  if ((tid & 63) == 0) ws[tid >> 6] = __popcll(m);
  __syncthreads();
  if (tid == 0) { int s = 0; for (int k = 0; k < 16; ++k) s += ws[k]; cnt[b] = s; }
}

__global__ void pos_prefix(int* __restrict__ cnt, int nb)
{
  if (threadIdx.x == 0) {
    int s = 0;
    for (int b = 0; b < nb; ++b) { int c = cnt[b]; cnt[b] = s; s += c; }
  }
}

__global__ __launch_bounds__(1024) void pos_scatter(const int* __restrict__ lbl, int n,
                                                    const int* __restrict__ cntp,
                                                    int* __restrict__ pos, int P)
{
  int b = blockIdx.x, tid = threadIdx.x;
  int i = b * 1024 + tid;
  int pred = (i < n) && (lbl[i] > 0);
  unsigned long long m = __ballot(pred);
  __shared__ int ws[16];
  int wid = tid >> 6, lane = tid & 63;
  if (lane == 0) ws[wid] = __popcll(m);
  __syncthreads();
  int wbase = 0;
  for (int w2 = 0; w2 < wid; ++w2) wbase += ws[w2];
  int rank = cntp[b] + wbase + __popcll(m & ((1ull << lane) - 1ull));
  if (pred && rank < P) pos[rank] = i;
}

// ---------------- gather positives + sq norms + bf16 copy ----------------
__global__ void gather_sq(const float* __restrict__ H, const int* __restrict__ pos,
                          float* __restrict__ X, unsigned short* __restrict__ Xh,
                          float* __restrict__ sq)
{
  int r = blockIdx.x, t = threadIdx.x;  // 128 threads
  int src = pos[r];
  float4 v = *(const float4*)&H[src * 512 + t * 4];
  *(float4*)&X[r * 512 + t * 4] = v;
  ushort4 hv;
  hv.x = f2bf(v.x); hv.y = f2bf(v.y); hv.z = f2bf(v.z); hv.w = f2bf(v.w);
  *(ushort4*)&Xh[r * 512 + t * 4] = hv;
  float s = v.x * v.x + v.y * v.y + v.z * v.z + v.w * v.w;
#pragma unroll
  for (int off = 32; off > 0; off >>= 1) s += __shfl_down(s, off);
  __shared__ float red[2];
  if ((t & 63) == 0) red[t >> 6] = s;
  __syncthreads();
  if (t == 0) sq[r] = red[0] + red[1];
}

// ------ symmetric Gram: one block per upper-tri 128x128 tile, dual scan -------
// dl stride 34 (8B-aligned rows) for paired f32x2 scan reads.
__global__ __launch_bounds__(256, 4) void gram_sym(
    const unsigned short* __restrict__ Xh, const float* __restrict__ sq,
    float* __restrict__ p8v, int* __restrict__ p8j)
{
  __shared__ char smem[34816];
  __shared__ float sqi_l[128], sqj_l[128];
  unsigned short* Ah = (unsigned short*)smem;
  unsigned short* Bh = (unsigned short*)(smem + 16384);
  float (*dl)[64][34] = (float (*)[64][34])(void*)smem;   // 34816B overlay
  float* mv = (float*)smem;
  int*   mj = (int*)(smem + 8192);

  const int tid = threadIdx.x;
  const int w = tid >> 6, lane = tid & 63;
  const int wr = w >> 1, wc = w & 1;
  const int fr = lane & 15, fg = lane >> 4;
  const int srow = tid >> 3;
  const int scb  = (tid & 7) << 4;

  int t = blockIdx.x;
  int a = (int)(64.5f - sqrtf(64.5f * 64.5f - 2.0f * (float)t));
  if (a < 0) a = 0;
  while (a > 0 && (a * (129 - a)) / 2 > t) --a;
  while (((a + 1) * (128 - a)) / 2 <= t) ++a;
  int b = a + (t - (a * (129 - a)) / 2);
  const int ai0 = a * 128, bj0 = b * 128;

  if (tid < 128) { sqi_l[tid] = sq[ai0 + tid]; sqj_l[tid] = sq[bj0 + tid]; }

  f32x4 acc[4][4];
#pragma unroll
  for (int mi = 0; mi < 4; ++mi)
#pragma unroll
    for (int ni = 0; ni < 4; ++ni) acc[mi][ni] = (f32x4){0.f, 0.f, 0.f, 0.f};

  for (int kt = 0; kt < 512; kt += 64) {
#pragma unroll
    for (int it = 0; it < 4; ++it) {
      int row = srow + it * 32;
      int cb = scb ^ ((row & 7) << 4);
      gload_lds16(&Xh[(size_t)(ai0 + row) * 512 + kt + (cb >> 1)],
                  &Ah[row * 64 + (scb >> 1)]);
      gload_lds16(&Xh[(size_t)(bj0 + row) * 512 + kt + (cb >> 1)],
                  &Bh[row * 64 + (scb >> 1)]);
    }
    __syncthreads();
#pragma unroll
    for (int ks = 0; ks < 2; ++ks) {
      bf16x8 af[4], bfr[4];
      int kb = ks * 64 + fg * 16;
#pragma unroll
      for (int mi = 0; mi < 4; ++mi) {
        int row = wr * 64 + mi * 16 + fr;
        af[mi] = *(const bf16x8*)&Ah[row * 64 + ((kb ^ ((row & 7) << 4)) >> 1)];
      }
#pragma unroll
      for (int ni = 0; ni < 4; ++ni) {
        int row = wc * 64 + ni * 16 + fr;
        bfr[ni] = *(const bf16x8*)&Bh[row * 64 + ((kb ^ ((row & 7) << 4)) >> 1)];
      }
#pragma unroll
      for (int mi = 0; mi < 4; ++mi)
#pragma unroll
        for (int ni = 0; ni < 4; ++ni)
          acc[mi][ni] = __builtin_amdgcn_mfma_f32_16x16x32_bf16(
              af[mi], bfr[ni], acc[mi][ni], 0, 0, 0);
    }
    __syncthreads();
  }

  float t8[8]; int j8[8];
#pragma unroll
  for (int q = 0; q < 8; ++q) { t8[q] = NEG_INF; j8[q] = 0x7fffffff; }

  // insertion (identical semantics to sequential scan)
  auto INS = [&](float v, int j) {
    t8[7] = v; j8[7] = j;
#pragma unroll
    for (int q = 7; q > 0; --q)
      if (t8[q] > t8[q - 1]) {
        float tv = t8[q]; t8[q] = t8[q - 1]; t8[q - 1] = tv;
        int tj = j8[q]; j8[q] = j8[q - 1]; j8[q - 1] = tj;
      }
  };

  // ---- direction 1: rows of a, candidates = cols of b (v = 2*dot - sq_j) ----
#pragma unroll
  for (int qp = 0; qp < 2; ++qp) {
#pragma unroll
    for (int qh = 0; qh < 2; ++qh) {
      int qn = qp * 2 + qh;
      float sqv = sqj_l[wc * 64 + qn * 16 + fr];
#pragma unroll
      for (int mi = 0; mi < 4; ++mi)
#pragma unroll
        for (int r = 0; r < 4; ++r)
          dl[w][mi * 16 + fg * 4 + r][qh * 16 + fr] = 2.0f * acc[mi][qn][r] - sqv;
    }
    __syncthreads();
    int jbase = bj0 + wc * 64 + qp * 32;
    for (int c = 0; c < 32; c += 2) {
      f32x2 pv = *(const f32x2*)&dl[w][lane][c];
      if (fmaxf(pv[0], pv[1]) > t8[7]) {
        if (pv[0] > t8[7]) INS(pv[0], jbase + c);
        if (pv[1] > t8[7]) INS(pv[1], jbase + c + 1);
      }
    }
    __syncthreads();
  }
#pragma unroll
  for (int q = 0; q < 8; ++q) {
    mv[(w * 64 + lane) * 8 + q] = t8[q];
    mj[(w * 64 + lane) * 8 + q] = j8[q];
  }
  __syncthreads();
  if ((w & 1) == 0) {
    int row = ai0 + (w >> 1) * 64 + lane;
    const float* v0 = &mv[(w * 64 + lane) * 8];
    const int*   c0 = &mj[(w * 64 + lane) * 8];
    const float* v1 = &mv[((w + 1) * 64 + lane) * 8];
    const int*   c1 = &mj[((w + 1) * 64 + lane) * 8];
    size_t ob = ((size_t)row * 64 + b) * 8;
    int h0 = 0, h1 = 0;
    for (int k = 0; k < 8; ++k) {
      float a0 = (h0 < 8) ? v0[h0] : NEG_INF;
      float a1 = (h1 < 8) ? v1[h1] : NEG_INF;
      int   b0 = (h0 < 8) ? c0[h0] : 0x7fffffff;
      int   b1 = (h1 < 8) ? c1[h1] : 0x7fffffff;
      bool take0 = (a0 > a1) || (a0 == a1 && b0 < b1);
      p8v[ob + k] = take0 ? a0 : a1;
      p8j[ob + k] = take0 ? b0 : b1;
      if (take0) ++h0; else ++h1;
    }
  }

  if (a != b) {
    __syncthreads();
#pragma unroll
    for (int q = 0; q < 8; ++q) { t8[q] = NEG_INF; j8[q] = 0x7fffffff; }
    // ---- direction 2: rows of b, candidates = rows of a (v = 2*dot - sq_i) ----
#pragma unroll
    for (int mp = 0; mp < 2; ++mp) {
#pragma unroll
      for (int mh = 0; mh < 2; ++mh) {
        int mi = mp * 2 + mh;
        f32x4 sv = *(const f32x4*)&sqi_l[wr * 64 + mi * 16 + fg * 4];
#pragma unroll
        for (int ni = 0; ni < 4; ++ni)
#pragma unroll
          for (int r = 0; r < 4; ++r)
            dl[w][ni * 16 + fr][mh * 16 + fg * 4 + r] = 2.0f * acc[mi][ni][r] - sv[r];
      }
      __syncthreads();
      int ibase = ai0 + wr * 64 + mp * 32;
      for (int c = 0; c < 32; c += 2) {
        f32x2 pv = *(const f32x2*)&dl[w][lane][c];
        if (fmaxf(pv[0], pv[1]) > t8[7]) {
          if (pv[0] > t8[7]) INS(pv[0], ibase + c);
          if (pv[1] > t8[7]) INS(pv[1], ibase + c + 1);
        }
      }
      __syncthreads();
    }
#pragma unroll
    for (int q = 0; q < 8; ++q) {
      mv[(w * 64 + lane) * 8 + q] = t8[q];
      mj[(w * 64 + lane) * 8 + q] = j8[q];
    }
    __syncthreads();
    if (wr == 0) {
      int row = bj0 + wc * 64 + lane;
      const float* v0 = &mv[(w * 64 + lane) * 8];
      const int*   c0 = &mj[(w * 64 + lane) * 8];
      const float* v1 = &mv[((w + 2) * 64 + lane) * 8];
      const int*   c1 = &mj[((w + 2) * 64 + lane) * 8];
      size_t ob = ((size_t)row * 64 + a) * 8;
      int h0 = 0, h1 = 0;
      for (int k = 0; k < 8; ++k) {
        float a0 = (h0 < 8) ? v0[h0] : NEG_INF;
        float a1 = (h1 < 8) ? v1[h1] : NEG_INF;
        int   b0 = (h0 < 8) ? c0[h0] : 0x7fffffff;
        int   b1 = (h1 < 8) ? c1[h1] : 0x7fffffff;
        bool take0 = (a0 > a1) || (a0 == a1 && b0 < b1);
        p8v[ob + k] = take0 ? a0 : a1;
        p8j[ob + k] = take0 ? b0 : b1;
        if (take0) ++h0; else ++h1;
      }
    }
  }
}

// ------- wave-parallel merge: 64 sorted lists (one per lane) -> top-8 ---------
__global__ __launch_bounds__(256) void merge8w(const float* __restrict__ p8v,
                                               const int* __restrict__ p8j,
                                               int* __restrict__ cand, int P)
{
  int row = blockIdx.x * 4 + (threadIdx.x >> 6);
  int lane = threadIdx.x & 63;
  if (row >= P) return;
  const float* v = p8v + (size_t)row * 512 + lane * 8;
  const int* j = p8j + (size_t)row * 512 + lane * 8;
  float vv[8]; int jj[8];
#pragma unroll
  for (int q = 0; q < 8; ++q) { vv[q] = v[q]; jj[q] = j[q]; }
  for (int k = 0; k < 8; ++k) {
    float cv = vv[0]; int cj = jj[0];
#pragma unroll
    for (int off = 1; off < 64; off <<= 1) {
      float ov = __shfl_xor(cv, off);
      int oj = __shfl_xor(cj, off);
      if (ov > cv || (ov == cv && oj < cj)) { cv = ov; cj = oj; }
    }
    if (lane == 0) cand[row * 8 + k] = cj;
    if (jj[0] == cj) {
#pragma unroll
      for (int q = 0; q < 7; ++q) { vv[q] = vv[q + 1]; jj[q] = jj[q + 1]; }
      vv[7] = NEG_INF; jj[7] = 0x7fffffff;
    }
  }
}

// ---------------- exact fp32 rescore of 8 candidates -> top-3 --------------
__global__ __launch_bounds__(64) void rescore(
    const float* __restrict__ X, const float* __restrict__ sq,
    const int* __restrict__ cand, int* __restrict__ idx3)
{
  int i = blockIdx.x;
  int lane = threadIdx.x;
  f32x4 x0 = *(const f32x4*)&X[(size_t)i * 512 + lane * 8];
  f32x4 x1 = *(const f32x4*)&X[(size_t)i * 512 + lane * 8 + 4];
  float d[8]; int cj[8];
#pragma unroll
  for (int c = 0; c < 8; ++c) {
    int j = cand[i * 8 + c];
    cj[c] = j;
    f32x4 y0 = *(const f32x4*)&X[(size_t)j * 512 + lane * 8];
    f32x4 y1 = *(const f32x4*)&X[(size_t)j * 512 + lane * 8 + 4];
    float p = x0.x * y0.x + x0.y * y0.y + x0.z * y0.z + x0.w * y0.w
            + x1.x * y1.x + x1.y * y1.y + x1.z * y1.z + x1.w * y1.w;
#pragma unroll
    for (int off = 32; off > 0; off >>= 1) p += __shfl_xor(p, off);
    d[c] = 2.0f * p - sq[i] - sq[j];
  }
  if (lane == 0) {
    for (int k = 0; k < 3; ++k) {
      int b = 0;
#pragma unroll
      for (int c = 1; c < 8; ++c)
        if (d[c] > d[b] || (d[c] == d[b] && cj[c] < cj[b])) b = c;
      idx3[i * 3 + k] = cj[b];
      d[b] = NEG_INF; cj[b] = 0x7fffffff;
    }
  }
}

// ---------------- SMOTE lerp rows: one block per i, 3 outputs -------------
__global__ void make_newfea(const float* __restrict__ X, const int* __restrict__ idx3,
                            const float* __restrict__ lw, float* __restrict__ out)
{
  int i = blockIdx.x;
  int t = threadIdx.x;          // 128 threads
  int ai = idx3[i * 3 + 0];
  float4 av = *(const float4*)&X[(size_t)ai * 512 + t * 4];
  *(float4*)&out[(size_t)(i * 3) * 512 + t * 4] = av;   // k=0: b==a -> a exactly
#pragma unroll
  for (int k = 1; k < 3; ++k) {
    int bi = idx3[i * 3 + k];
    float w = lw[i * 3 + k];
    float4 bv = *(const float4*)&X[(size_t)bi * 512 + t * 4];
    float4 o;
    o.x = av.x + w * (bv.x - av.x);
    o.y = av.y + w * (bv.y - av.y);
    o.z = av.z + w * (bv.z - av.z);
    o.w = av.w + w * (bv.w - av.w);
    *(float4*)&out[(size_t)(i * 3 + k) * 512 + t * 4] = o;
  }
}

__global__ void write_lbl(const int* __restrict__ lbl, float* __restrict__ out,
                          int n_in, int n_total)
{
  int i = blockIdx.x * blockDim.x + threadIdx.x;
  if (i < n_total) out[i] = (i < n_in) ? (float)lbl[i] : 1.0f;
}

// ---------------- launch ----------------
extern "C" void kernel_launch(void* const* d_in, const int* in_sizes, int n_in,
                              void* d_out, int out_size, void* d_ws, size_t ws_size,
                              hipStream_t stream)
{
  const float* fea   = (const float*)d_in[0];
  const int*   lbl   = (const int*)d_in[1];
  const float* W1    = (const float*)d_in[2];
  const float* b1    = (const float*)d_in[3];
  const float* g1    = (const float*)d_in[4];
  const float* beta1 = (const float*)d_in[5];
  const float* W2    = (const float*)d_in[6];
  const float* b2    = (const float*)d_in[7];
  const float* g2    = (const float*)d_in[8];
  const float* beta2 = (const float*)d_in[9];
  const float* lerp_w = (const float*)d_in[10];

  int bs = in_sizes[0] / 512;       // 32768
  int P  = in_sizes[10] / 3;        // 8192
  int n_total = bs + 3 * P;         // 57344

  float* out_f = (float*)d_out;
  float* Hout = out_f;
  float* newfea = out_f + (size_t)bs * 512;
  float* lbl_out = out_f + (size_t)n_total * 512;

  const size_t MB = 1024 * 1024;
  const size_t KB = 1024;
  char* ws = (char*)d_ws;
  float* Y1 = (float*)ws;                                  // 64MB fp32 y1 -> h1
  float* X  = (float*)(ws + 64 * MB);                      // 16MB (after weights dead)
  unsigned short* W1h = (unsigned short*)(ws + 64 * MB);
  unsigned short* W1m = (unsigned short*)(ws + 64 * MB + 512 * KB);
  unsigned short* W1l = (unsigned short*)(ws + 64 * MB + 1024 * KB);
  unsigned short* W2h = (unsigned short*)(ws + 64 * MB + 1536 * KB);
  unsigned short* W2m = (unsigned short*)(ws + 64 * MB + 2048 * KB);
  unsigned short* W2l = (unsigned short*)(ws + 64 * MB + 2560 * KB);
  float* partial = (float*)(ws + 80 * MB);                 // 2MB
  float* scale = (float*)(ws + 82 * MB);
  float* shiftv = scale + 512;
  float* sq = shiftv + 512;
  int* pos = (int*)(sq + 8192);
  int* idx3 = pos + 8192;
  int* cnt = idx3 + 3 * 8192;
  float* partial2 = (float*)(ws + 83 * MB);                // 64KB
  // overlays in dead Y1 region (used only after gemm2):
  unsigned short* Xh = (unsigned short*)ws;                // 8MB
  float* p8v = (float*)(ws + 8 * MB);                      // 16MB (8192 x 64 x 8)
  int*   p8j = (int*)(ws + 24 * MB);                       // 16MB
  int*   cand = (int*)(ws + 40 * MB);                      // 256KB

  dim3 wgrid(8, 8);
  split_w_t3<<<wgrid, 256, 0, stream>>>(W1, W1h, W1m, W1l);
  split_w_t3<<<wgrid, 256, 0, stream>>>(W2, W2h, W2m, W2l);

  dim3 ggrid(bs / 128, 4);
  int nslot = (bs / 128) * 2;          // 512
  dim3 rgrid(16, 2);

  gemm_split3<<<ggrid, 256, 0, stream>>>(fea, W1h, W1m, W1l, b1, Y1, partial);
  bn_reduce1<<<rgrid, 256, 0, stream>>>(partial, partial2, nslot);
  bn_finalize<<<2, 256, 0, stream>>>(partial2, g1, beta1, scale, shiftv, bs);
  bn_swish<<<(bs * 512 / 4 + 255) / 256, 256, 0, stream>>>(Y1, scale, shiftv, Y1, bs * 512 / 4);

  gemm_split3<<<ggrid, 256, 0, stream>>>(Y1, W2h, W2m, W2l, b2, Hout, partial);
  bn_reduce1<<<rgrid, 256, 0, stream>>>(partial, partial2, nslot);
  bn_finalize<<<2, 256, 0, stream>>>(partial2, g2, beta2, scale, shiftv, bs);
  bn_swish<<<(bs * 512 / 4 + 255) / 256, 256, 0, stream>>>(Hout, scale, shiftv, Hout, bs * 512 / 4);

  int nb = (bs + 1023) / 1024;         // 32
  pos_count<<<nb, 1024, 0, stream>>>(lbl, bs, cnt, pos, P);
  pos_prefix<<<1, 64, 0, stream>>>(cnt, nb);
  pos_scatter<<<nb, 1024, 0, stream>>>(lbl, bs, cnt, pos, P);
  gather_sq<<<P, 128, 0, stream>>>(Hout, pos, X, Xh, sq);

  int nbk = P / 128;                    // 64
  int ntri = nbk * (nbk + 1) / 2;       // 2080
  gram_sym<<<ntri, 256, 0, stream>>>(Xh, sq, p8v, p8j);
  merge8w<<<(P + 3) / 4, 256, 0, stream>>>(p8v, p8j, cand, P);
  rescore<<<P, 64, 0, stream>>>(X, sq, cand, idx3);

  make_newfea<<<P, 128, 0, stream>>>(X, idx3, lerp_w, newfea);
  write_lbl<<<(n_total + 255) / 256, 256, 0, stream>>>(lbl, lbl_out, bs, n_total);
}

// Round 13
// 453.590 us; speedup vs baseline: 1.0895x; 1.0380x over previous
//
#include <hip/hip_runtime.h>
#include <math.h>

#define NEG_INF -3.402823466e38f

typedef __attribute__((ext_vector_type(8))) short bf16x8;
typedef __attribute__((ext_vector_type(4))) float f32x4;

__device__ __forceinline__ void gload_lds16(const unsigned short* g, unsigned short* l) {
  __builtin_amdgcn_global_load_lds(
      (const __attribute__((address_space(1))) unsigned int*)g,
      (__attribute__((address_space(3))) unsigned int*)l, 16, 0, 0);
}
__device__ __forceinline__ void gload_lds16f(const float* g, float* l) {
  __builtin_amdgcn_global_load_lds(
      (const __attribute__((address_space(1))) unsigned int*)g,
      (__attribute__((address_space(3))) unsigned int*)l, 16, 0, 0);
}

__device__ __forceinline__ unsigned short f2bf(float f) {
  union { float f; unsigned int u; } a; a.f = f;
  unsigned int u = a.u;
  return (unsigned short)((u + 0x7fffu + ((u >> 16) & 1u)) >> 16);
}

// pairwise 3-term truncation split: 8 f32 -> hi/mid/lo bf16x8.
__device__ __forceinline__ void split3_8(f32x4 a, f32x4 b,
                                         bf16x8& hi, bf16x8& md, bf16x8& lo) {
  union { bf16x8 v; unsigned int u[4]; } H, M, L;
  float f[8];
  f[0]=a[0]; f[1]=a[1]; f[2]=a[2]; f[3]=a[3];
  f[4]=b[0]; f[5]=b[1]; f[6]=b[2]; f[7]=b[3];
#pragma unroll
  for (int p = 0; p < 4; ++p) {
    union { float f; unsigned int u; } x0, x1, h0, h1, r0, r1, m0, m1, s0, s1;
    x0.f = f[2*p]; x1.f = f[2*p+1];
    H.u[p] = (x0.u >> 16) | (x1.u & 0xffff0000u);
    h0.u = x0.u & 0xffff0000u; h1.u = x1.u & 0xffff0000u;
    r0.f = x0.f - h0.f;        r1.f = x1.f - h1.f;
    M.u[p] = (r0.u >> 16) | (r1.u & 0xffff0000u);
    m0.u = r0.u & 0xffff0000u; m1.u = r1.u & 0xffff0000u;
    s0.f = r0.f - m0.f;        s1.f = r1.f - m1.f;
    L.u[p] = (s0.u >> 16) | (s1.u & 0xffff0000u);
  }
  hi = H.v; md = M.v; lo = L.v;
}

// ------ split+transpose weights: W[512][512] -> Wt_{h,m,l}[n][k] --------------
__global__ __launch_bounds__(256) void split_w_t3(const float* __restrict__ W,
    unsigned short* __restrict__ Th, unsigned short* __restrict__ Tm,
    unsigned short* __restrict__ Tl)
{
  __shared__ float T[64][65];
  int k0 = blockIdx.x * 64, n0 = blockIdx.y * 64;
  int tid = threadIdx.x;
  int r = tid >> 4, c4 = (tid & 15) << 2;
#pragma unroll
  for (int p = 0; p < 4; ++p) {
    int row = r + p * 16;
    float4 v = *(const float4*)&W[(size_t)(k0 + row) * 512 + n0 + c4];
    T[c4 + 0][row] = v.x; T[c4 + 1][row] = v.y;
    T[c4 + 2][row] = v.z; T[c4 + 3][row] = v.w;
  }
  __syncthreads();
  int nr = tid >> 2, kc = (tid & 3) << 4;
#pragma unroll
  for (int u = 0; u < 16; ++u) {
    union { float f; unsigned int u; } x, h, rr, m, ss;
    x.f = T[nr][kc + u];
    unsigned short hb = (unsigned short)(x.u >> 16);
    h.u = x.u & 0xffff0000u;
    rr.f = x.f - h.f;
    unsigned short mb = (unsigned short)(rr.u >> 16);
    m.u = rr.u & 0xffff0000u;
    ss.f = rr.f - m.f;
    unsigned short lb = (unsigned short)(ss.u >> 16);
    size_t o = (size_t)(n0 + nr) * 512 + k0 + kc + u;
    Th[o] = hb; Tm[o] = mb; Tl[o] = lb;
  }
}

// ------ GEMM: dbuf BK=32, wave = 32 rows x 128 cols (2 splits/iter) -----------
__global__ __launch_bounds__(256, 2) void gemm_split3(
    const float* __restrict__ A, const unsigned short* __restrict__ Bth,
    const unsigned short* __restrict__ Btm, const unsigned short* __restrict__ Btl,
    const float* __restrict__ bias, float* __restrict__ C, float* __restrict__ partial)
{
  __shared__ char smem[81920];   // 2 x (sA 16K + 3x8K B)
  const int tid = threadIdx.x;
  const int w = tid >> 6, lane = tid & 63;
  const int bm = blockIdx.x * 128, bn = blockIdx.y * 128;
  const int fr = lane & 15, fg = lane >> 4;
  const int arow = tid >> 3, acb = (tid & 7) << 4;
  const int brow = tid >> 2, bcb = (tid & 3) << 4;

  f32x4 acc[2][8];
#pragma unroll
  for (int mi = 0; mi < 2; ++mi)
#pragma unroll
    for (int ni = 0; ni < 8; ++ni) acc[mi][ni] = (f32x4){0.f, 0.f, 0.f, 0.f};

  auto STAGE = [&](int buf, int ktf) {
    float* sA = (float*)(smem + buf * 40960);
    unsigned short* sBh = (unsigned short*)(smem + buf * 40960 + 16384);
    unsigned short* sBm = sBh + 4096;
    unsigned short* sBl = sBm + 4096;
#pragma unroll
    for (int p = 0; p < 4; ++p) {
      int row = arow + p * 32;
      int cb = acb ^ ((row & 7) << 4);
      gload_lds16f(&A[(size_t)(bm + row) * 512 + ktf + (cb >> 2)],
                   &sA[row * 32 + (acb >> 2)]);
    }
#pragma unroll
    for (int p = 0; p < 2; ++p) {
      int row = brow + p * 64;
      int cb = bcb ^ (((row >> 1) & 3) << 4);
      int so = row * 32 + (bcb >> 1);
      gload_lds16(&Bth[(size_t)(bn + row) * 512 + ktf + (cb >> 1)], &sBh[so]);
      gload_lds16(&Btm[(size_t)(bn + row) * 512 + ktf + (cb >> 1)], &sBm[so]);
      gload_lds16(&Btl[(size_t)(bn + row) * 512 + ktf + (cb >> 1)], &sBl[so]);
    }
  };

  STAGE(0, 0);
  __syncthreads();
  for (int it = 0; it < 16; ++it) {
    int cur = it & 1;
    if (it + 1 < 16) STAGE(cur ^ 1, (it + 1) * 32);
    float* sA = (float*)(smem + cur * 40960);
    unsigned short* sBh = (unsigned short*)(smem + cur * 40960 + 16384);
    unsigned short* sBm = sBh + 4096;
    unsigned short* sBl = sBm + 4096;
    bf16x8 ah[2], am[2], al[2];
#pragma unroll
    for (int mi = 0; mi < 2; ++mi) {
      int row = w * 32 + mi * 16 + fr;
      int swz = (row & 7) << 4;
      const char* rb = (const char*)(sA + row * 32);
      f32x4 f0 = *(const f32x4*)(rb + ((fg * 32) ^ swz));
      f32x4 f1 = *(const f32x4*)(rb + ((fg * 32 + 16) ^ swz));
      split3_8(f0, f1, ah[mi], am[mi], al[mi]);
    }
#pragma unroll
    for (int ni = 0; ni < 8; ++ni) {
      int row = ni * 16 + fr;
      int off = row * 32 + (((fg * 16) ^ (((row >> 1) & 3) << 4)) >> 1);
      bf16x8 bh  = *(const bf16x8*)&sBh[off];
      bf16x8 bmf = *(const bf16x8*)&sBm[off];
      bf16x8 blf = *(const bf16x8*)&sBl[off];
#pragma unroll
      for (int mi = 0; mi < 2; ++mi) {
        acc[mi][ni] = __builtin_amdgcn_mfma_f32_16x16x32_bf16(al[mi], bh,  acc[mi][ni], 0, 0, 0);
        acc[mi][ni] = __builtin_amdgcn_mfma_f32_16x16x32_bf16(am[mi], bmf, acc[mi][ni], 0, 0, 0);
        acc[mi][ni] = __builtin_amdgcn_mfma_f32_16x16x32_bf16(ah[mi], blf, acc[mi][ni], 0, 0, 0);
        acc[mi][ni] = __builtin_amdgcn_mfma_f32_16x16x32_bf16(am[mi], bh,  acc[mi][ni], 0, 0, 0);
        acc[mi][ni] = __builtin_amdgcn_mfma_f32_16x16x32_bf16(ah[mi], bmf, acc[mi][ni], 0, 0, 0);
        acc[mi][ni] = __builtin_amdgcn_mfma_f32_16x16x32_bf16(ah[mi], bh,  acc[mi][ni], 0, 0, 0);
      }
    }
    __syncthreads();
  }

  float ssv[8], qqv[8];
#pragma unroll
  for (int ni = 0; ni < 8; ++ni) {
    float bno = bias[bn + ni * 16 + fr];
    float s = 0.f, q = 0.f;
#pragma unroll
    for (int mi = 0; mi < 2; ++mi) {
      int row = bm + w * 32 + mi * 16 + fg * 4;
      int col = bn + ni * 16 + fr;
#pragma unroll
      for (int r = 0; r < 4; ++r) {
        float v = acc[mi][ni][r] + bno;
        C[(size_t)(row + r) * 512 + col] = v;
        s += v; q += v * v;
      }
    }
    s += __shfl_xor(s, 16); s += __shfl_xor(s, 32);
    q += __shfl_xor(q, 16); q += __shfl_xor(q, 32);
    ssv[ni] = s; qqv[ni] = q;
  }
  float* ps = (float*)smem;
  if (fg == 0) {
#pragma unroll
    for (int ni = 0; ni < 8; ++ni) {
      ps[((w * 2 + 0) * 8 + ni) * 16 + fr] = ssv[ni];
      ps[((w * 2 + 1) * 8 + ni) * 16 + fr] = qqv[ni];
    }
  }
  __syncthreads();
  if ((w & 1) == 0) {
    int p = w >> 1;
#pragma unroll
    for (int k = 0; k < 4; ++k) {
      int idx = k * 64 + lane;
      int part = idx >> 7;
      int rem = idx & 127;
      int ni = rem >> 4, fr2 = rem & 15;
      float v = ps[(((2 * p) * 2 + part) * 8 + ni) * 16 + fr2]
              + ps[(((2 * p + 1) * 2 + part) * 8 + ni) * 16 + fr2];
      int slot = blockIdx.x * 2 + p;
      partial[(size_t)(slot * 2 + part) * 512 + bn + ni * 16 + fr2] = v;
    }
  }
}

// ------ BN reduce stage 1 --------
__global__ __launch_bounds__(256) void bn_reduce1(
    const float* __restrict__ partial, float* __restrict__ partial2, int nslot)
{
  int g = blockIdx.x, p = blockIdx.y;
  int per = nslot >> 4;
  int t = threadIdx.x;
#pragma unroll
  for (int cc = 0; cc < 2; ++cc) {
    int c = t + cc * 256;
    float s = 0.f;
    for (int s0 = 0; s0 < per; ++s0) {
      int slot = g * per + s0;
      s += partial[(size_t)(slot * 2 + p) * 512 + c];
    }
    partial2[(size_t)(g * 2 + p) * 512 + c] = s;
  }
}

__global__ void bn_finalize(
    const float* __restrict__ partial2, const float* __restrict__ g,
    const float* __restrict__ beta, float* __restrict__ scale,
    float* __restrict__ shift, int rows)
{
  int c = blockIdx.x * blockDim.x + threadIdx.x;
  if (c >= 512) return;
  float s = 0, s2 = 0;
  for (int b = 0; b < 16; ++b) {
    s  += partial2[(size_t)(b * 2 + 0) * 512 + c];
    s2 += partial2[(size_t)(b * 2 + 1) * 512 + c];
  }
  float m = s / rows;
  float v = s2 / rows - m * m;
  if (v < 0) v = 0;
  float sc = g[c] / sqrtf(v + 1e-5f);
  scale[c] = sc;
  shift[c] = beta[c] - m * sc;
}

__global__ void bn_swish(
    const float* __restrict__ Y, const float* __restrict__ scale,
    const float* __restrict__ shift, float* __restrict__ H, int total4)
{
  int i = blockIdx.x * blockDim.x + threadIdx.x;
  if (i >= total4) return;
  float4 y = ((const float4*)Y)[i];
  int c = (i * 4) & 511;
  float z;
  float4 o;
  z = y.x * scale[c + 0] + shift[c + 0]; o.x = z / (1.f + expf(-z));
  z = y.y * scale[c + 1] + shift[c + 1]; o.y = z / (1.f + expf(-z));
  z = y.z * scale[c + 2] + shift[c + 2]; o.z = z / (1.f + expf(-z));
  z = y.w * scale[c + 3] + shift[c + 3]; o.w = z / (1.f + expf(-z));
  ((float4*)H)[i] = o;
}

// ---------------- positive-label compaction: 3-kernel scan ----------------
__global__ __launch_bounds__(1024) void pos_count(const int* __restrict__ lbl, int n,
                                                  int* __restrict__ cnt,
                                                  int* __restrict__ pos, int P)
{
  int b = blockIdx.x, tid = threadIdx.x;
  int i = b * 1024 + tid;
  if (i < P) pos[i] = 0;
  int pred = (i < n) && (lbl[i] > 0);
  unsigned long long m = __ballot(pred);
  __shared__ int ws[16];
  if ((tid & 63) == 0) ws[tid >> 6] = __popcll(m);
  __syncthreads();
  if (tid == 0) { int s = 0; for (int k = 0; k < 16; ++k) s += ws[k]; cnt[b] = s; }
}

__global__ void pos_prefix(int* __restrict__ cnt, int nb)
{
  if (threadIdx.x == 0) {
    int s = 0;
    for (int b = 0; b < nb; ++b) { int c = cnt[b]; cnt[b] = s; s += c; }
  }
}

__global__ __launch_bounds__(1024) void pos_scatter(const int* __restrict__ lbl, int n,
                                                    const int* __restrict__ cntp,
                                                    int* __restrict__ pos, int P)
{
  int b = blockIdx.x, tid = threadIdx.x;
  int i = b * 1024 + tid;
  int pred = (i < n) && (lbl[i] > 0);
  unsigned long long m = __ballot(pred);
  __shared__ int ws[16];
  int wid = tid >> 6, lane = tid & 63;
  if (lane == 0) ws[wid] = __popcll(m);
  __syncthreads();
  int wbase = 0;
  for (int w2 = 0; w2 < wid; ++w2) wbase += ws[w2];
  int rank = cntp[b] + wbase + __popcll(m & ((1ull << lane) - 1ull));
  if (pred && rank < P) pos[rank] = i;
}

// ---------------- gather positives + sq norms + bf16 copy ----------------
__global__ void gather_sq(const float* __restrict__ H, const int* __restrict__ pos,
                          float* __restrict__ X, unsigned short* __restrict__ Xh,
                          float* __restrict__ sq)
{
  int r = blockIdx.x, t = threadIdx.x;  // 128 threads
  int src = pos[r];
  float4 v = *(const float4*)&H[src * 512 + t * 4];
  *(float4*)&X[r * 512 + t * 4] = v;
  ushort4 hv;
  hv.x = f2bf(v.x); hv.y = f2bf(v.y); hv.z = f2bf(v.z); hv.w = f2bf(v.w);
  *(ushort4*)&Xh[r * 512 + t * 4] = hv;
  float s = v.x * v.x + v.y * v.y + v.z * v.z + v.w * v.w;
#pragma unroll
  for (int off = 32; off > 0; off >>= 1) s += __shfl_down(s, off);
  __shared__ float red[2];
  if ((t & 63) == 0) red[t >> 6] = s;
  __syncthreads();
  if (t == 0) sq[r] = red[0] + red[1];
}

// ------ symmetric Gram: one block per upper-tri 128x128 tile, dual scan -------
// (round-10 best-measured config: dl[64][33], sequential scan, 4 blocks/CU)
__global__ __launch_bounds__(256, 4) void gram_sym(
    const unsigned short* __restrict__ Xh, const float* __restrict__ sq,
    float* __restrict__ p8v, int* __restrict__ p8j)
{
  __shared__ char smem[33792];
  __shared__ float sqi_l[128], sqj_l[128];
  unsigned short* Ah = (unsigned short*)smem;
  unsigned short* Bh = (unsigned short*)(smem + 16384);
  float (*dl)[64][33] = (float (*)[64][33])(void*)smem;
  float* mv = (float*)smem;
  int*   mj = (int*)(smem + 8192);

  const int tid = threadIdx.x;
  const int w = tid >> 6, lane = tid & 63;
  const int wr = w >> 1, wc = w & 1;
  const int fr = lane & 15, fg = lane >> 4;
  const int srow = tid >> 3;
  const int scb  = (tid & 7) << 4;

  int t = blockIdx.x;
  int a = (int)(64.5f - sqrtf(64.5f * 64.5f - 2.0f * (float)t));
  if (a < 0) a = 0;
  while (a > 0 && (a * (129 - a)) / 2 > t) --a;
  while (((a + 1) * (128 - a)) / 2 <= t) ++a;
  int b = a + (t - (a * (129 - a)) / 2);
  const int ai0 = a * 128, bj0 = b * 128;

  if (tid < 128) { sqi_l[tid] = sq[ai0 + tid]; sqj_l[tid] = sq[bj0 + tid]; }

  f32x4 acc[4][4];
#pragma unroll
  for (int mi = 0; mi < 4; ++mi)
#pragma unroll
    for (int ni = 0; ni < 4; ++ni) acc[mi][ni] = (f32x4){0.f, 0.f, 0.f, 0.f};

  for (int kt = 0; kt < 512; kt += 64) {
#pragma unroll
    for (int it = 0; it < 4; ++it) {
      int row = srow + it * 32;
      int cb = scb ^ ((row & 7) << 4);
      gload_lds16(&Xh[(size_t)(ai0 + row) * 512 + kt + (cb >> 1)],
                  &Ah[row * 64 + (scb >> 1)]);
      gload_lds16(&Xh[(size_t)(bj0 + row) * 512 + kt + (cb >> 1)],
                  &Bh[row * 64 + (scb >> 1)]);
    }
    __syncthreads();
#pragma unroll
    for (int ks = 0; ks < 2; ++ks) {
      bf16x8 af[4], bfr[4];
      int kb = ks * 64 + fg * 16;
#pragma unroll
      for (int mi = 0; mi < 4; ++mi) {
        int row = wr * 64 + mi * 16 + fr;
        af[mi] = *(const bf16x8*)&Ah[row * 64 + ((kb ^ ((row & 7) << 4)) >> 1)];
      }
#pragma unroll
      for (int ni = 0; ni < 4; ++ni) {
        int row = wc * 64 + ni * 16 + fr;
        bfr[ni] = *(const bf16x8*)&Bh[row * 64 + ((kb ^ ((row & 7) << 4)) >> 1)];
      }
#pragma unroll
      for (int mi = 0; mi < 4; ++mi)
#pragma unroll
        for (int ni = 0; ni < 4; ++ni)
          acc[mi][ni] = __builtin_amdgcn_mfma_f32_16x16x32_bf16(
              af[mi], bfr[ni], acc[mi][ni], 0, 0, 0);
    }
    __syncthreads();
  }

  float t8[8]; int j8[8];
#pragma unroll
  for (int q = 0; q < 8; ++q) { t8[q] = NEG_INF; j8[q] = 0x7fffffff; }

  // ---- direction 1: rows of a, candidates = cols of b (v = 2*dot - sq_j) ----
#pragma unroll
  for (int qp = 0; qp < 2; ++qp) {
#pragma unroll
    for (int qh = 0; qh < 2; ++qh) {
      int qn = qp * 2 + qh;
      float sqv = sqj_l[wc * 64 + qn * 16 + fr];
#pragma unroll
      for (int mi = 0; mi < 4; ++mi)
#pragma unroll
        for (int r = 0; r < 4; ++r)
          dl[w][mi * 16 + fg * 4 + r][qh * 16 + fr] = 2.0f * acc[mi][qn][r] - sqv;
    }
    __syncthreads();
    int jbase = bj0 + wc * 64 + qp * 32;
    for (int c = 0; c < 32; ++c) {
      float v = dl[w][lane][c];
      if (v > t8[7]) {
        t8[7] = v; j8[7] = jbase + c;
#pragma unroll
        for (int q = 7; q > 0; --q)
          if (t8[q] > t8[q - 1]) {
            float tv = t8[q]; t8[q] = t8[q - 1]; t8[q - 1] = tv;
            int tj = j8[q]; j8[q] = j8[q - 1]; j8[q - 1] = tj;
          }
      }
    }
    __syncthreads();
  }
#pragma unroll
  for (int q = 0; q < 8; ++q) {
    mv[(w * 64 + lane) * 8 + q] = t8[q];
    mj[(w * 64 + lane) * 8 + q] = j8[q];
  }
  __syncthreads();
  if ((w & 1) == 0) {
    int row = ai0 + (w >> 1) * 64 + lane;
    const float* v0 = &mv[(w * 64 + lane) * 8];
    const int*   c0 = &mj[(w * 64 + lane) * 8];
    const float* v1 = &mv[((w + 1) * 64 + lane) * 8];
    const int*   c1 = &mj[((w + 1) * 64 + lane) * 8];
    size_t ob = ((size_t)row * 64 + b) * 8;
    int h0 = 0, h1 = 0;
    for (int k = 0; k < 8; ++k) {
      float a0 = (h0 < 8) ? v0[h0] : NEG_INF;
      float a1 = (h1 < 8) ? v1[h1] : NEG_INF;
      int   b0 = (h0 < 8) ? c0[h0] : 0x7fffffff;
      int   b1 = (h1 < 8) ? c1[h1] : 0x7fffffff;
      bool take0 = (a0 > a1) || (a0 == a1 && b0 < b1);
      p8v[ob + k] = take0 ? a0 : a1;
      p8j[ob + k] = take0 ? b0 : b1;
      if (take0) ++h0; else ++h1;
    }
  }

  if (a != b) {
    __syncthreads();
#pragma unroll
    for (int q = 0; q < 8; ++q) { t8[q] = NEG_INF; j8[q] = 0x7fffffff; }
    // ---- direction 2: rows of b, candidates = rows of a (v = 2*dot - sq_i) ----
#pragma unroll
    for (int mp = 0; mp < 2; ++mp) {
#pragma unroll
      for (int mh = 0; mh < 2; ++mh) {
        int mi = mp * 2 + mh;
        f32x4 sv = *(const f32x4*)&sqi_l[wr * 64 + mi * 16 + fg * 4];
#pragma unroll
        for (int ni = 0; ni < 4; ++ni)
#pragma unroll
          for (int r = 0; r < 4; ++r)
            dl[w][ni * 16 + fr][mh * 16 + fg * 4 + r] = 2.0f * acc[mi][ni][r] - sv[r];
      }
      __syncthreads();
      int ibase = ai0 + wr * 64 + mp * 32;
      for (int c = 0; c < 32; ++c) {
        float v = dl[w][lane][c];
        if (v > t8[7]) {
          t8[7] = v; j8[7] = ibase + c;
#pragma unroll
          for (int q = 7; q > 0; --q)
            if (t8[q] > t8[q - 1]) {
              float tv = t8[q]; t8[q] = t8[q - 1]; t8[q - 1] = tv;
              int tj = j8[q]; j8[q] = j8[q - 1]; j8[q - 1] = tj;
            }
        }
      }
      __syncthreads();
    }
#pragma unroll
    for (int q = 0; q < 8; ++q) {
      mv[(w * 64 + lane) * 8 + q] = t8[q];
      mj[(w * 64 + lane) * 8 + q] = j8[q];
    }
    __syncthreads();
    if (wr == 0) {
      int row = bj0 + wc * 64 + lane;
      const float* v0 = &mv[(w * 64 + lane) * 8];
      const int*   c0 = &mj[(w * 64 + lane) * 8];
      const float* v1 = &mv[((w + 2) * 64 + lane) * 8];
      const int*   c1 = &mj[((w + 2) * 64 + lane) * 8];
      size_t ob = ((size_t)row * 64 + a) * 8;
      int h0 = 0, h1 = 0;
      for (int k = 0; k < 8; ++k) {
        float a0 = (h0 < 8) ? v0[h0] : NEG_INF;
        float a1 = (h1 < 8) ? v1[h1] : NEG_INF;
        int   b0 = (h0 < 8) ? c0[h0] : 0x7fffffff;
        int   b1 = (h1 < 8) ? c1[h1] : 0x7fffffff;
        bool take0 = (a0 > a1) || (a0 == a1 && b0 < b1);
        p8v[ob + k] = take0 ? a0 : a1;
        p8j[ob + k] = take0 ? b0 : b1;
        if (take0) ++h0; else ++h1;
      }
    }
  }
}

// ------- wave-parallel merge: 64 sorted lists (one per lane) -> top-8 ---------
__global__ __launch_bounds__(256) void merge8w(const float* __restrict__ p8v,
                                               const int* __restrict__ p8j,
                                               int* __restrict__ cand, int P)
{
  int row = blockIdx.x * 4 + (threadIdx.x >> 6);
  int lane = threadIdx.x & 63;
  if (row >= P) return;
  const float* v = p8v + (size_t)row * 512 + lane * 8;
  const int* j = p8j + (size_t)row * 512 + lane * 8;
  float vv[8]; int jj[8];
#pragma unroll
  for (int q = 0; q < 8; ++q) { vv[q] = v[q]; jj[q] = j[q]; }
  for (int k = 0; k < 8; ++k) {
    float cv = vv[0]; int cj = jj[0];
#pragma unroll
    for (int off = 1; off < 64; off <<= 1) {
      float ov = __shfl_xor(cv, off);
      int oj = __shfl_xor(cj, off);
      if (ov > cv || (ov == cv && oj < cj)) { cv = ov; cj = oj; }
    }
    if (lane == 0) cand[row * 8 + k] = cj;
    if (jj[0] == cj) {
#pragma unroll
      for (int q = 0; q < 7; ++q) { vv[q] = vv[q + 1]; jj[q] = jj[q + 1]; }
      vv[7] = NEG_INF; jj[7] = 0x7fffffff;
    }
  }
}

// ---------------- exact fp32 rescore of 8 candidates -> top-3 --------------
__global__ __launch_bounds__(64) void rescore(
    const float* __restrict__ X, const float* __restrict__ sq,
    const int* __restrict__ cand, int* __restrict__ idx3)
{
  int i = blockIdx.x;
  int lane = threadIdx.x;
  f32x4 x0 = *(const f32x4*)&X[(size_t)i * 512 + lane * 8];
  f32x4 x1 = *(const f32x4*)&X[(size_t)i * 512 + lane * 8 + 4];
  float d[8]; int cj[8];
#pragma unroll
  for (int c = 0; c < 8; ++c) {
    int j = cand[i * 8 + c];
    cj[c] = j;
    f32x4 y0 = *(const f32x4*)&X[(size_t)j * 512 + lane * 8];
    f32x4 y1 = *(const f32x4*)&X[(size_t)j * 512 + lane * 8 + 4];
    float p = x0.x * y0.x + x0.y * y0.y + x0.z * y0.z + x0.w * y0.w
            + x1.x * y1.x + x1.y * y1.y + x1.z * y1.z + x1.w * y1.w;
#pragma unroll
    for (int off = 32; off > 0; off >>= 1) p += __shfl_xor(p, off);
    d[c] = 2.0f * p - sq[i] - sq[j];
  }
  if (lane == 0) {
    for (int k = 0; k < 3; ++k) {
      int b = 0;
#pragma unroll
      for (int c = 1; c < 8; ++c)
        if (d[c] > d[b] || (d[c] == d[b] && cj[c] < cj[b])) b = c;
      idx3[i * 3 + k] = cj[b];
      d[b] = NEG_INF; cj[b] = 0x7fffffff;
    }
  }
}

// ---------------- SMOTE lerp rows: one block per i, 3 outputs -------------
__global__ void make_newfea(const float* __restrict__ X, const int* __restrict__ idx3,
                            const float* __restrict__ lw, float* __restrict__ out)
{
  int i = blockIdx.x;
  int t = threadIdx.x;          // 128 threads
  int ai = idx3[i * 3 + 0];
  float4 av = *(const float4*)&X[(size_t)ai * 512 + t * 4];
  *(float4*)&out[(size_t)(i * 3) * 512 + t * 4] = av;   // k=0: b==a -> a exactly
#pragma unroll
  for (int k = 1; k < 3; ++k) {
    int bi = idx3[i * 3 + k];
    float w = lw[i * 3 + k];
    float4 bv = *(const float4*)&X[(size_t)bi * 512 + t * 4];
    float4 o;
    o.x = av.x + w * (bv.x - av.x);
    o.y = av.y + w * (bv.y - av.y);
    o.z = av.z + w * (bv.z - av.z);
    o.w = av.w + w * (bv.w - av.w);
    *(float4*)&out[(size_t)(i * 3 + k) * 512 + t * 4] = o;
  }
}

__global__ void write_lbl(const int* __restrict__ lbl, float* __restrict__ out,
                          int n_in, int n_total)
{
  int i = blockIdx.x * blockDim.x + threadIdx.x;
  if (i < n_total) out[i] = (i < n_in) ? (float)lbl[i] : 1.0f;
}

// ---------------- launch ----------------
extern "C" void kernel_launch(void* const* d_in, const int* in_sizes, int n_in,
                              void* d_out, int out_size, void* d_ws, size_t ws_size,
                              hipStream_t stream)
{
  const float* fea   = (const float*)d_in[0];
  const int*   lbl   = (const int*)d_in[1];
  const float* W1    = (const float*)d_in[2];
  const float* b1    = (const float*)d_in[3];
  const float* g1    = (const float*)d_in[4];
  const float* beta1 = (const float*)d_in[5];
  const float* W2    = (const float*)d_in[6];
  const float* b2    = (const float*)d_in[7];
  const float* g2    = (const float*)d_in[8];
  const float* beta2 = (const float*)d_in[9];
  const float* lerp_w = (const float*)d_in[10];

  int bs = in_sizes[0] / 512;       // 32768
  int P  = in_sizes[10] / 3;        // 8192
  int n_total = bs + 3 * P;         // 57344

  float* out_f = (float*)d_out;
  float* Hout = out_f;
  float* newfea = out_f + (size_t)bs * 512;
  float* lbl_out = out_f + (size_t)n_total * 512;

  const size_t MB = 1024 * 1024;
  const size_t KB = 1024;
  char* ws = (char*)d_ws;
  float* Y1 = (float*)ws;                                  // 64MB fp32 y1 -> h1
  float* X  = (float*)(ws + 64 * MB);                      // 16MB (after weights dead)
  unsigned short* W1h = (unsigned short*)(ws + 64 * MB);
  unsigned short* W1m = (unsigned short*)(ws + 64 * MB + 512 * KB);
  unsigned short* W1l = (unsigned short*)(ws + 64 * MB + 1024 * KB);
  unsigned short* W2h = (unsigned short*)(ws + 64 * MB + 1536 * KB);
  unsigned short* W2m = (unsigned short*)(ws + 64 * MB + 2048 * KB);
  unsigned short* W2l = (unsigned short*)(ws + 64 * MB + 2560 * KB);
  float* partial = (float*)(ws + 80 * MB);                 // 2MB
  float* scale = (float*)(ws + 82 * MB);
  float* shiftv = scale + 512;
  float* sq = shiftv + 512;
  int* pos = (int*)(sq + 8192);
  int* idx3 = pos + 8192;
  int* cnt = idx3 + 3 * 8192;
  float* partial2 = (float*)(ws + 83 * MB);                // 64KB
  // overlays in dead Y1 region (used only after gemm2):
  unsigned short* Xh = (unsigned short*)ws;                // 8MB
  float* p8v = (float*)(ws + 8 * MB);                      // 16MB (8192 x 64 x 8)
  int*   p8j = (int*)(ws + 24 * MB);                       // 16MB
  int*   cand = (int*)(ws + 40 * MB);                      // 256KB

  dim3 wgrid(8, 8);
  split_w_t3<<<wgrid, 256, 0, stream>>>(W1, W1h, W1m, W1l);
  split_w_t3<<<wgrid, 256, 0, stream>>>(W2, W2h, W2m, W2l);

  dim3 ggrid(bs / 128, 4);
  int nslot = (bs / 128) * 2;          // 512
  dim3 rgrid(16, 2);

  gemm_split3<<<ggrid, 256, 0, stream>>>(fea, W1h, W1m, W1l, b1, Y1, partial);
  bn_reduce1<<<rgrid, 256, 0, stream>>>(partial, partial2, nslot);
  bn_finalize<<<2, 256, 0, stream>>>(partial2, g1, beta1, scale, shiftv, bs);
  bn_swish<<<(bs * 512 / 4 + 255) / 256, 256, 0, stream>>>(Y1, scale, shiftv, Y1, bs * 512 / 4);

  gemm_split3<<<ggrid, 256, 0, stream>>>(Y1, W2h, W2m, W2l, b2, Hout, partial);
  bn_reduce1<<<rgrid, 256, 0, stream>>>(partial, partial2, nslot);
  bn_finalize<<<2, 256, 0, stream>>>(partial2, g2, beta2, scale, shiftv, bs);
  bn_swish<<<(bs * 512 / 4 + 255) / 256, 256, 0, stream>>>(Hout, scale, shiftv, Hout, bs * 512 / 4);

  int nb = (bs + 1023) / 1024;         // 32
  pos_count<<<nb, 1024, 0, stream>>>(lbl, bs, cnt, pos, P);
  pos_prefix<<<1, 64, 0, stream>>>(cnt, nb);
  pos_scatter<<<nb, 1024, 0, stream>>>(lbl, bs, cnt, pos, P);
  gather_sq<<<P, 128, 0, stream>>>(Hout, pos, X, Xh, sq);

  int nbk = P / 128;                    // 64
  int ntri = nbk * (nbk + 1) / 2;       // 2080
  gram_sym<<<ntri, 256, 0, stream>>>(Xh, sq, p8v, p8j);
  merge8w<<<(P + 3) / 4, 256, 0, stream>>>(p8v, p8j, cand, P);
  rescore<<<P, 64, 0, stream>>>(X, sq, cand, idx3);

  make_newfea<<<P, 128, 0, stream>>>(X, idx3, lerp_w, newfea);
  write_lbl<<<(n_total + 255) / 256, 256, 0, stream>>>(lbl, lbl_out, bs, n_total);
}